// Round 11
// baseline (86.323 us; speedup 1.0000x reference)
//
#include <hip/hip_runtime.h>

#define NV 100000
#define NJ 24
#define NP 207
#define VPB 8
#define NTILES (NV / VPB)      // 12500
#define TF4 1242               // float4 per tile = VPB*621/4
#define GRIDM 1024

// ---------------------------------------------------------------------------
// Stage one 8-vertex posedirs tile (1242 float4) into LDS via DMA.
// All 4 waves issue exactly 5 global_load_lds -> uniform vmcnt accounting.
// ---------------------------------------------------------------------------
__device__ __forceinline__ void stage_tile(float4* dst, const float4* src, int tid) {
  #pragma unroll
  for (int r = 0; r < 5; ++r) {
    int i4 = r * 256 + tid;
    if (i4 < TF4) {
      __builtin_amdgcn_global_load_lds(
          (const __attribute__((address_space(1))) void*)(src + i4),
          (__attribute__((address_space(3))) void*)(dst + r * 256 + (tid & 192)),
          16, 0, 0);
    }
  }
}

// ---------------------------------------------------------------------------
// K1: fused streaming kernel. R6's strided counted-vmcnt tile pipeline for
// the posedirs dot, with shape-blend + J-partial accumulation riding inside
// (lrotmin needs only pose -> computed in-block; J needed only later for rel).
// Outputs: v_posed -> vbuf, J partials -> jpT[72][1024].
// ---------------------------------------------------------------------------
__global__ __launch_bounds__(256, 4) void k_main(
    const float* __restrict__ betas, const float* __restrict__ pose,
    const float* __restrict__ v_template, const float* __restrict__ shapedirs,
    const float* __restrict__ posedirs, const float* __restrict__ Jreg,
    float* __restrict__ vbuf, float* __restrict__ jpT) {
  __shared__ float4 tile[2][TF4];   // 39744 B
  __shared__ float lrs[NP];         // 828 B   (total 40572 <= 40960)
  int tid = threadIdx.x, b = blockIdx.x;
  int wid = tid >> 6, lane = tid & 63, half = lane >> 5, lj = lane & 31;
  const float4* pd4 = (const float4*)posedirs;

  // prologue DMA: tile b into buffer 0
  stage_tile(&tile[0][0], pd4 + (size_t)b * TF4, tid);

  // in-block rodrigues -> lrotmin (wave 0, lanes 1..23 write 9 each)
  if (tid < NJ) {
    float rx = pose[tid * 3 + 0], ry = pose[tid * 3 + 1], rz = pose[tid * 3 + 2];
    float tx = rx + 1e-8f, ty = ry + 1e-8f, tz = rz + 1e-8f;
    float theta = sqrtf(tx * tx + ty * ty + tz * tz);
    float x = rx / theta, y = ry / theta, z = rz / theta;
    float c = cosf(theta), s = sinf(theta), C = 1.f - c;
    if (tid >= 1) {
      float Rr[9];
      Rr[0] = c + C * x * x;     Rr[1] = C * x * y - s * z; Rr[2] = C * x * z + s * y;
      Rr[3] = C * x * y + s * z; Rr[4] = c + C * y * y;     Rr[5] = C * y * z - s * x;
      Rr[6] = C * x * z - s * y; Rr[7] = C * y * z + s * x; Rr[8] = c + C * z * z;
      #pragma unroll
      for (int e = 0; e < 9; ++e) {
        float id = (e == 0 || e == 4 || e == 8) ? 1.f : 0.f;
        lrs[(tid - 1) * 9 + e] = Rr[e] - id;
      }
    }
  }
  __syncthreads();  // lrs visible (also drains prologue DMA once)

  float llr[7];
  #pragma unroll
  for (int e = 0; e < 7; ++e) {
    int p = lj + 32 * e;
    llr[e] = (p < NP) ? lrs[p] : 0.f;
  }
  float bt = 0.f;
  if (lj < 30) {
    int s = lj >= 20 ? lj - 20 : (lj >= 10 ? lj - 10 : lj);
    bt = betas[s];
  }

  float jacc0 = 0.f, jacc1 = 0.f, jacc2 = 0.f;
  int nt = (NTILES - 1 - b) / GRIDM + 1;

  for (int it = 0; it < nt; ++it) {
    int cur = it & 1;
    int vv = (b + it * GRIDM) * VPB + (wid << 1) + half;
    // per-iter loads FIRST (older than the 5 stage ops -> covered by vmcnt(5))
    float sdv = (lj < 30) ? shapedirs[(size_t)vv * 30 + lj] : 0.f;
    float vtv = (lj < 3) ? v_template[(size_t)3 * vv + lj] : 0.f;
    float jw  = (lj < NJ) ? Jreg[(size_t)lj * NV + vv] : 0.f;
    __builtin_amdgcn_sched_barrier(0);  // pin loads above the stage ops
    int tnext = b + (it + 1) * GRIDM;
    if (tnext >= NTILES) tnext = NTILES - 1;  // dummy on last iter
    stage_tile(&tile[cur ^ 1][0], pd4 + (size_t)tnext * TF4, tid);
    asm volatile("s_waitcnt vmcnt(5)" ::: "memory");
    __builtin_amdgcn_sched_barrier(0);
    __builtin_amdgcn_s_barrier();
    __builtin_amdgcn_sched_barrier(0);

    // v_shaped: masked segment products, 5-round xor reduce over 32 lanes
    float xx = sdv * bt;
    float r0 = (lj < 10) ? xx : 0.f;
    float r1 = (lj >= 10 && lj < 20) ? xx : 0.f;
    float r2 = (lj >= 20 && lj < 30) ? xx : 0.f;
    #pragma unroll
    for (int off = 16; off > 0; off >>= 1) {
      r0 += __shfl_xor(r0, off);
      r1 += __shfl_xor(r1, off);
      r2 += __shfl_xor(r2, off);
    }
    int gb = lane & 32;
    r0 += __shfl(vtv, gb + 0);
    r1 += __shfl(vtv, gb + 1);
    r2 += __shfl(vtv, gb + 2);

    // posedirs dot from LDS tile
    const float* row = (const float*)&tile[cur][0] + ((wid << 1) + half) * (3 * NP);
    float a0 = 0.f, a1 = 0.f, a2 = 0.f;
    #pragma unroll
    for (int e = 0; e < 7; ++e) {
      int p = lj + 32 * e;
      if (p < NP) {
        float l = llr[e];
        a0 += row[p] * l;
        a1 += row[NP + p] * l;
        a2 += row[2 * NP + p] * l;
      }
    }
    #pragma unroll
    for (int off = 16; off > 0; off >>= 1) {
      a0 += __shfl_xor(a0, off);
      a1 += __shfl_xor(a1, off);
      a2 += __shfl_xor(a2, off);
    }

    // v_posed store + J-partial accumulate (J = Jreg @ v_shaped)
    if (lj < 3) {
      float oo = (lj == 0) ? r0 + a0 : (lj == 1) ? r1 + a1 : r2 + a2;
      vbuf[(size_t)3 * vv + lj] = oo;
    }
    jacc0 += jw * r0;
    jacc1 += jw * r1;
    jacc2 += jw * r2;

    __builtin_amdgcn_sched_barrier(0);
    __builtin_amdgcn_s_barrier();
    __builtin_amdgcn_sched_barrier(0);
  }
  asm volatile("s_waitcnt vmcnt(0)" ::: "memory");  // drain dummy stage
  __syncthreads();

  // block-reduce J partials: halves, then waves (reuse tile LDS as scratch)
  jacc0 += __shfl_xor(jacc0, 32);
  jacc1 += __shfl_xor(jacc1, 32);
  jacc2 += __shfl_xor(jacc2, 32);
  float* jred = (float*)&tile[0][0];  // [4][24][3]
  if (half == 0 && lj < NJ) {
    jred[(wid * NJ + lj) * 3 + 0] = jacc0;
    jred[(wid * NJ + lj) * 3 + 1] = jacc1;
    jred[(wid * NJ + lj) * 3 + 2] = jacc2;
  }
  __syncthreads();
  if (tid < NJ * 3) {  // tid = j*3+k
    float s = jred[tid] + jred[NJ * 3 + tid] + jred[2 * NJ * 3 + tid] + jred[3 * NJ * 3 + tid];
    jpT[(size_t)tid * GRIDM + b] = s;
  }
}

// ---------------------------------------------------------------------------
// K2: single block: reduce jpT[72][1024] (contiguous float4 streams),
// rodrigues, FK chain, rel matrices.
// ---------------------------------------------------------------------------
__global__ __launch_bounds__(128) void k_fk(
    const float* __restrict__ pose, const float* __restrict__ jpT,
    float* __restrict__ rel) {
  __shared__ float J[NJ * 3];
  __shared__ float R[NJ][9];
  __shared__ float G[NJ][12];
  int tid = threadIdx.x;
  if (tid < NJ * 3) {
    const float4* p4 = (const float4*)(jpT + (size_t)tid * GRIDM);
    float a = 0.f;
    #pragma unroll 8
    for (int i = 0; i < GRIDM / 4; ++i) {
      float4 x = p4[i];
      a += x.x + x.y + x.z + x.w;
    }
    J[tid] = a;
  }
  __syncthreads();
  if (tid < NJ) {
    float rx = pose[tid * 3 + 0], ry = pose[tid * 3 + 1], rz = pose[tid * 3 + 2];
    float tx = rx + 1e-8f, ty = ry + 1e-8f, tz = rz + 1e-8f;
    float theta = sqrtf(tx * tx + ty * ty + tz * tz);
    float x = rx / theta, y = ry / theta, z = rz / theta;
    float c = cosf(theta), s = sinf(theta), C = 1.f - c;
    float* Rr = R[tid];
    Rr[0] = c + C * x * x;     Rr[1] = C * x * y - s * z; Rr[2] = C * x * z + s * y;
    Rr[3] = C * x * y + s * z; Rr[4] = c + C * y * y;     Rr[5] = C * y * z - s * x;
    Rr[6] = C * x * z - s * y; Rr[7] = C * y * z + s * x; Rr[8] = c + C * z * z;
  }
  __syncthreads();
  if (tid == 0) {
    const int par[NJ] = {-1,0,0,0,1,2,3,4,5,6,7,8,9,9,9,12,13,14,16,17,18,19,20,21};
    for (int a = 0; a < 3; ++a) {
      for (int b = 0; b < 3; ++b) G[0][a * 4 + b] = R[0][a * 3 + b];
      G[0][a * 4 + 3] = J[a];
    }
    for (int i = 1; i < NJ; ++i) {
      int p = par[i];
      float t0 = J[i * 3 + 0] - J[p * 3 + 0];
      float t1 = J[i * 3 + 1] - J[p * 3 + 1];
      float t2 = J[i * 3 + 2] - J[p * 3 + 2];
      for (int a = 0; a < 3; ++a) {
        float g0 = G[p][a * 4 + 0], g1 = G[p][a * 4 + 1], g2 = G[p][a * 4 + 2];
        for (int b = 0; b < 3; ++b)
          G[i][a * 4 + b] = g0 * R[i][0 * 3 + b] + g1 * R[i][1 * 3 + b] + g2 * R[i][2 * 3 + b];
        G[i][a * 4 + 3] = G[p][a * 4 + 3] + g0 * t0 + g1 * t1 + g2 * t2;
      }
    }
  }
  __syncthreads();
  if (tid < NJ) {
    for (int a = 0; a < 3; ++a) {
      float corr = G[tid][a * 4 + 0] * J[tid * 3 + 0] +
                   G[tid][a * 4 + 1] * J[tid * 3 + 1] +
                   G[tid][a * 4 + 2] * J[tid * 3 + 2];
      rel[tid * 12 + a * 4 + 0] = G[tid][a * 4 + 0];
      rel[tid * 12 + a * 4 + 1] = G[tid][a * 4 + 1];
      rel[tid * 12 + a * 4 + 2] = G[tid][a * 4 + 2];
      rel[tid * 12 + a * 4 + 3] = G[tid][a * 4 + 3] - corr;
    }
  }
}

// ---------------------------------------------------------------------------
// K3: LBS + scale/trans. Reads v_posed from vbuf, overwrites with final.
// ---------------------------------------------------------------------------
__global__ __launch_bounds__(256) void k_lbs(
    const float* __restrict__ weights, const float* __restrict__ rel,
    const float* __restrict__ scale, const float* __restrict__ trans,
    float* __restrict__ vbuf) {
  __shared__ float rl[NJ * 12];
  int tid = threadIdx.x;
  for (int i = tid; i < NJ * 12; i += 256) rl[i] = rel[i];
  __syncthreads();
  int v = blockIdx.x * 256 + tid;
  if (v >= NV) return;
  float a0 = vbuf[v * 3 + 0], a1 = vbuf[v * 3 + 1], a2 = vbuf[v * 3 + 2];
  float4 w4[6];
  const float4* wv = (const float4*)(weights + (size_t)v * NJ);
  #pragma unroll
  for (int i = 0; i < 6; ++i) w4[i] = wv[i];
  const float* w = (const float*)w4;
  float T[12];
  #pragma unroll
  for (int e = 0; e < 12; ++e) T[e] = 0.f;
  #pragma unroll
  for (int j = 0; j < NJ; ++j) {
    float wj = w[j];
    #pragma unroll
    for (int e = 0; e < 12; ++e) T[e] += wj * rl[j * 12 + e];
  }
  float sc = scale[0];
  float o0 = T[0] * a0 + T[1] * a1 + T[2]  * a2 + T[3];
  float o1 = T[4] * a0 + T[5] * a1 + T[6]  * a2 + T[7];
  float o2 = T[8] * a0 + T[9] * a1 + T[10] * a2 + T[11];
  vbuf[v * 3 + 0] = o0 * sc + trans[0];
  vbuf[v * 3 + 1] = o1 * sc + trans[1];
  vbuf[v * 3 + 2] = o2 * sc + trans[2];
}

extern "C" void kernel_launch(void* const* d_in, const int* in_sizes, int n_in,
                              void* d_out, int out_size, void* d_ws, size_t ws_size,
                              hipStream_t stream) {
  const float* betas      = (const float*)d_in[0];
  const float* pose       = (const float*)d_in[1];
  const float* scale      = (const float*)d_in[2];
  const float* trans      = (const float*)d_in[3];
  const float* v_template = (const float*)d_in[4];
  const float* shapedirs  = (const float*)d_in[5];
  const float* posedirs   = (const float*)d_in[6];
  const float* Jreg       = (const float*)d_in[7];
  const float* weights    = (const float*)d_in[8];
  float* out = (float*)d_out;
  float* ws  = (float*)d_ws;

  float* jpT = ws;                 // 72*1024 = 73728 floats
  float* rel = ws + 73728;         // 288 floats

  k_main<<<GRIDM, 256, 0, stream>>>(betas, pose, v_template, shapedirs,
                                    posedirs, Jreg, out, jpT);
  k_fk<<<1, 128, 0, stream>>>(pose, jpT, rel);
  k_lbs<<<(NV + 255) / 256, 256, 0, stream>>>(weights, rel, scale, trans, out);
}

// Round 12
// 70.948 us; speedup vs baseline: 1.2167x; 1.2167x over previous
//
#include <hip/hip_runtime.h>

#define NV 100000
#define NJ 24
#define NP 207
#define NPART 25
#define VPB 8
#define NTILES (NV / VPB)      // 12500
#define TF4 1242               // float4 per tile = VPB*621/4
#define GRIDF 512              // 2 blocks/CU

// ---------------------------------------------------------------------------
// K1: v_shaped = v_template + shapedirs @ betas, flat over 300000 rows of 10.
// ---------------------------------------------------------------------------
__global__ __launch_bounds__(256) void k_shape(
    const float* __restrict__ betas, const float* __restrict__ v_template,
    const float* __restrict__ shapedirs, float* __restrict__ v_shaped) {
  __shared__ float sb[10];
  if (threadIdx.x < 10) sb[threadIdx.x] = betas[threadIdx.x];
  __syncthreads();
  int R = blockIdx.x * 256 + threadIdx.x;
  if (R >= 3 * NV) return;
  const float2* sd = (const float2*)(shapedirs + (size_t)R * 10);
  float a = v_template[R];
  #pragma unroll
  for (int s = 0; s < 5; ++s) {
    float2 x = sd[s];
    a += x.x * sb[2 * s] + x.y * sb[2 * s + 1];
  }
  v_shaped[R] = a;
}

// ---------------------------------------------------------------------------
// K2: J partials.  grid = (24 joints, 25 parts), pure float4 loads.
// ---------------------------------------------------------------------------
__global__ __launch_bounds__(256) void k_jreg(
    const float* __restrict__ Jreg, const float* __restrict__ v_shaped,
    float* __restrict__ jpart) {
  int j = blockIdx.x, part = blockIdx.y, tid = threadIdx.x;
  const int SL = NV / NPART;  // 4000
  int v0 = part * SL;
  const float4* w4 = (const float4*)(Jreg + (size_t)j * NV + v0);
  const float4* s4 = (const float4*)(v_shaped + (size_t)3 * v0);
  float s0 = 0.f, s1 = 0.f, s2 = 0.f;
  for (int i4 = tid; i4 < SL / 4; i4 += 256) {
    float4 w = w4[i4];
    float4 A = s4[3 * i4 + 0];
    float4 B = s4[3 * i4 + 1];
    float4 C = s4[3 * i4 + 2];
    s0 += w.x * A.x + w.y * A.w + w.z * B.z + w.w * C.y;
    s1 += w.x * A.y + w.y * B.x + w.z * B.w + w.w * C.z;
    s2 += w.x * A.z + w.y * B.y + w.z * C.x + w.w * C.w;
  }
  __shared__ float red[256][3];
  red[tid][0] = s0; red[tid][1] = s1; red[tid][2] = s2;
  __syncthreads();
  for (int off = 128; off > 0; off >>= 1) {
    if (tid < off) {
      red[tid][0] += red[tid + off][0];
      red[tid][1] += red[tid + off][1];
      red[tid][2] += red[tid + off][2];
    }
    __syncthreads();
  }
  if (tid < 3) jpart[(part * NJ + j) * 3 + tid] = red[0][tid];
}

// ---------------------------------------------------------------------------
// K3: single block: finalize J, rodrigues, FK chain, rel matrices, lrotmin
// ---------------------------------------------------------------------------
__global__ __launch_bounds__(64) void k_fk(
    const float* __restrict__ pose, const float* __restrict__ jpart,
    float* __restrict__ lrot, float* __restrict__ rel) {
  __shared__ float J[NJ][3];
  __shared__ float R[NJ][9];
  __shared__ float G[NJ][12];
  int tid = threadIdx.x;
  if (tid < NJ) {
    for (int k = 0; k < 3; ++k) {
      float a = 0.f;
      for (int part = 0; part < NPART; ++part) a += jpart[(part * NJ + tid) * 3 + k];
      J[tid][k] = a;
    }
    float rx = pose[tid * 3 + 0], ry = pose[tid * 3 + 1], rz = pose[tid * 3 + 2];
    float tx = rx + 1e-8f, ty = ry + 1e-8f, tz = rz + 1e-8f;
    float theta = sqrtf(tx * tx + ty * ty + tz * tz);
    float x = rx / theta, y = ry / theta, z = rz / theta;
    float c = cosf(theta), s = sinf(theta), C = 1.f - c;
    float* Rr = R[tid];
    Rr[0] = c + C * x * x;     Rr[1] = C * x * y - s * z; Rr[2] = C * x * z + s * y;
    Rr[3] = C * x * y + s * z; Rr[4] = c + C * y * y;     Rr[5] = C * y * z - s * x;
    Rr[6] = C * x * z - s * y; Rr[7] = C * y * z + s * x; Rr[8] = c + C * z * z;
    if (tid >= 1) {
      #pragma unroll
      for (int e = 0; e < 9; ++e) {
        float id = (e == 0 || e == 4 || e == 8) ? 1.f : 0.f;
        lrot[(tid - 1) * 9 + e] = Rr[e] - id;
      }
    }
  }
  __syncthreads();
  if (tid == 0) {
    const int par[NJ] = {-1,0,0,0,1,2,3,4,5,6,7,8,9,9,9,12,13,14,16,17,18,19,20,21};
    for (int a = 0; a < 3; ++a) {
      for (int b = 0; b < 3; ++b) G[0][a * 4 + b] = R[0][a * 3 + b];
      G[0][a * 4 + 3] = J[0][a];
    }
    for (int i = 1; i < NJ; ++i) {
      int p = par[i];
      float t0 = J[i][0] - J[p][0], t1 = J[i][1] - J[p][1], t2 = J[i][2] - J[p][2];
      for (int a = 0; a < 3; ++a) {
        float g0 = G[p][a * 4 + 0], g1 = G[p][a * 4 + 1], g2 = G[p][a * 4 + 2];
        for (int b = 0; b < 3; ++b)
          G[i][a * 4 + b] = g0 * R[i][0 * 3 + b] + g1 * R[i][1 * 3 + b] + g2 * R[i][2 * 3 + b];
        G[i][a * 4 + 3] = G[p][a * 4 + 3] + g0 * t0 + g1 * t1 + g2 * t2;
      }
    }
  }
  __syncthreads();
  if (tid < NJ) {
    for (int a = 0; a < 3; ++a) {
      float corr = G[tid][a * 4 + 0] * J[tid][0] + G[tid][a * 4 + 1] * J[tid][1] +
                   G[tid][a * 4 + 2] * J[tid][2];
      rel[tid * 12 + a * 4 + 0] = G[tid][a * 4 + 0];
      rel[tid * 12 + a * 4 + 1] = G[tid][a * 4 + 1];
      rel[tid * 12 + a * 4 + 2] = G[tid][a * 4 + 2];
      rel[tid * 12 + a * 4 + 3] = G[tid][a * 4 + 3] - corr;
    }
  }
}

// ---------------------------------------------------------------------------
// Stage one 8-vertex posedirs tile (1242 float4) into LDS via DMA.
// All 4 waves issue exactly 5 global_load_lds -> uniform vmcnt accounting.
// ---------------------------------------------------------------------------
__device__ __forceinline__ void stage_tile(float4* dst, const float4* src, int tid) {
  #pragma unroll
  for (int r = 0; r < 5; ++r) {
    int i4 = r * 256 + tid;
    if (i4 < TF4) {
      __builtin_amdgcn_global_load_lds(
          (const __attribute__((address_space(1))) void*)(src + i4),
          (__attribute__((address_space(3))) void*)(dst + r * 256 + (tid & 192)),
          16, 0, 0);
    }
  }
}

// ---------------------------------------------------------------------------
// K4: fused pose-blend + LBS. TRIPLE-buffered counted-vmcnt pipeline,
// grid=512 (2 blocks/CU): half the concurrent streams of R6, 2 tiles
// (40KB) in flight per block, 10MB contiguous collective front per
// lockstep iteration. Per-iter vmem ops: E = {pvl,wj for NEXT iter} (2),
// F = stage tile it+2 (5). vmcnt(10) leaves F_i(5)+E_i(2)+F_{i-1}(3)
// in flight and forces: all of stage(it) [compute tile], E_{i-1}
// [this iter's pvl/wj] -> compute phase has zero VM stalls.
// ---------------------------------------------------------------------------
__global__ __launch_bounds__(256, 2) void k_fused(
    const float* __restrict__ posedirs, const float* __restrict__ wgt,
    const float* __restrict__ lrot, const float* __restrict__ rel,
    const float* __restrict__ scale, const float* __restrict__ trans,
    float* __restrict__ vbuf) {
  __shared__ float4 tile[3][TF4];   // 59616 B
  int tid = threadIdx.x, b = blockIdx.x;
  int wid = tid >> 6, lane = tid & 63, half = lane >> 5, lj = lane & 31;
  const float4* pd4 = (const float4*)posedirs;

  // prologue: A = scalars for iter 0, B/D = tiles b, b+512
  int vv0 = b * VPB + (wid << 1) + half;
  float pvl = (lj < 3) ? vbuf[(size_t)3 * vv0 + lj] : 0.f;
  float wj  = (lj < NJ) ? wgt[(size_t)vv0 * NJ + lj] : 0.f;
  __builtin_amdgcn_sched_barrier(0);
  stage_tile(&tile[0][0], pd4 + (size_t)b * TF4, tid);
  stage_tile(&tile[1][0], pd4 + (size_t)(b + GRIDF) * TF4, tid);

  // C: per-lane constants (counted but never in the newest-10 window)
  float llr[7];
  #pragma unroll
  for (int e = 0; e < 7; ++e) {
    int p = lj + 32 * e;
    llr[e] = (p < NP) ? lrot[p] : 0.f;
  }
  float rlq[12];
  #pragma unroll
  for (int e = 0; e < 12; ++e) rlq[e] = (lj < NJ) ? rel[lj * 12 + e] : 0.f;
  float sc = scale[0];
  float tr = (lj < 3) ? trans[lj] : 0.f;

  float4* bc = &tile[0][0];
  float4* bn = &tile[1][0];
  float4* bs = &tile[2][0];
  int nt = (NTILES - 1 - b) / GRIDF + 1;  // 24 or 25

  for (int it = 0; it < nt; ++it) {
    // E: prefetch NEXT iteration's scalars (clamped on last iter)
    int tnE = b + (it + 1) * GRIDF;
    if (tnE >= NTILES) tnE = NTILES - 1;
    int vvn = tnE * VPB + (wid << 1) + half;
    float pvl_n = (lj < 3) ? vbuf[(size_t)3 * vvn + lj] : 0.f;
    float wj_n  = (lj < NJ) ? wgt[(size_t)vvn * NJ + lj] : 0.f;
    __builtin_amdgcn_sched_barrier(0);
    // F: stage tile it+2 (dummy clamped on the tail)
    int tst = b + (it + 2) * GRIDF;
    if (tst >= NTILES) tst = NTILES - 1;
    stage_tile(bs, pd4 + (size_t)tst * TF4, tid);
    asm volatile("s_waitcnt vmcnt(10)" ::: "memory");
    __builtin_amdgcn_sched_barrier(0);
    __builtin_amdgcn_s_barrier();
    __builtin_amdgcn_sched_barrier(0);

    int vv = (b + it * GRIDF) * VPB + (wid << 1) + half;
    const float* row = (const float*)bc + ((wid << 1) + half) * (3 * NP);
    float a0 = 0.f, a1 = 0.f, a2 = 0.f;
    #pragma unroll
    for (int e = 0; e < 7; ++e) {
      int p = lj + 32 * e;
      if (p < NP) {
        float l = llr[e];
        a0 += row[p] * l;
        a1 += row[NP + p] * l;
        a2 += row[2 * NP + p] * l;
      }
    }
    #pragma unroll
    for (int off = 16; off > 0; off >>= 1) {
      a0 += __shfl_xor(a0, off);
      a1 += __shfl_xor(a1, off);
      a2 += __shfl_xor(a2, off);
    }
    int gb = lane & 32;
    float p0 = __shfl(pvl, gb + 0) + a0;
    float p1 = __shfl(pvl, gb + 1) + a1;
    float p2 = __shfl(pvl, gb + 2) + a2;
    float q0 = rlq[0] * p0 + rlq[1] * p1 + rlq[2]  * p2 + rlq[3];
    float q1 = rlq[4] * p0 + rlq[5] * p1 + rlq[6]  * p2 + rlq[7];
    float q2 = rlq[8] * p0 + rlq[9] * p1 + rlq[10] * p2 + rlq[11];
    float r0 = wj * q0, r1 = wj * q1, r2 = wj * q2;
    #pragma unroll
    for (int off = 16; off > 0; off >>= 1) {
      r0 += __shfl_xor(r0, off);
      r1 += __shfl_xor(r1, off);
      r2 += __shfl_xor(r2, off);
    }
    if (lj < 3) {
      float oo = (lj == 0) ? r0 : (lj == 1) ? r1 : r2;
      vbuf[(size_t)3 * vv + lj] = oo * sc + tr;
    }
    __builtin_amdgcn_sched_barrier(0);
    __builtin_amdgcn_s_barrier();
    __builtin_amdgcn_sched_barrier(0);

    pvl = pvl_n; wj = wj_n;
    float4* tmp = bc; bc = bn; bn = bs; bs = tmp;
  }
  asm volatile("s_waitcnt vmcnt(0)" ::: "memory");  // drain tail dummies
}

extern "C" void kernel_launch(void* const* d_in, const int* in_sizes, int n_in,
                              void* d_out, int out_size, void* d_ws, size_t ws_size,
                              hipStream_t stream) {
  const float* betas      = (const float*)d_in[0];
  const float* pose       = (const float*)d_in[1];
  const float* scale      = (const float*)d_in[2];
  const float* trans      = (const float*)d_in[3];
  const float* v_template = (const float*)d_in[4];
  const float* shapedirs  = (const float*)d_in[5];
  const float* posedirs   = (const float*)d_in[6];
  const float* Jreg       = (const float*)d_in[7];
  const float* weights    = (const float*)d_in[8];
  float* out = (float*)d_out;
  float* ws  = (float*)d_ws;

  float* jpart = ws;          // 25*24*3 = 1800 floats
  float* lrot  = ws + 1800;   // 207 floats
  float* rel   = ws + 2048;   // 288 floats

  k_shape<<<(3 * NV + 255) / 256, 256, 0, stream>>>(betas, v_template, shapedirs, out);
  k_jreg<<<dim3(NJ, NPART), 256, 0, stream>>>(Jreg, out, jpart);
  k_fk<<<1, 64, 0, stream>>>(pose, jpart, lrot, rel);
  k_fused<<<GRIDF, 256, 0, stream>>>(posedirs, weights, lrot, rel, scale, trans, out);
}

// Round 13
// 67.474 us; speedup vs baseline: 1.2794x; 1.0515x over previous
//
#include <hip/hip_runtime.h>

#define NV 100000
#define NJ 24
#define NP 207
#define NPART 25
#define VPB 8
#define NTILES (NV / VPB)      // 12500
#define TF4 1242               // float4 per tile = VPB*621/4
#define GRIDF 1024

// ---------------------------------------------------------------------------
// K1: v_shaped = v_template + shapedirs @ betas, flat over 300000 rows of 10.
// ---------------------------------------------------------------------------
__global__ __launch_bounds__(256) void k_shape(
    const float* __restrict__ betas, const float* __restrict__ v_template,
    const float* __restrict__ shapedirs, float* __restrict__ v_shaped) {
  __shared__ float sb[10];
  if (threadIdx.x < 10) sb[threadIdx.x] = betas[threadIdx.x];
  __syncthreads();
  int R = blockIdx.x * 256 + threadIdx.x;
  if (R >= 3 * NV) return;
  const float2* sd = (const float2*)(shapedirs + (size_t)R * 10);
  float a = v_template[R];
  #pragma unroll
  for (int s = 0; s < 5; ++s) {
    float2 x = sd[s];
    a += x.x * sb[2 * s] + x.y * sb[2 * s + 1];
  }
  v_shaped[R] = a;
}

// ---------------------------------------------------------------------------
// K2: J partials.  grid = (24 joints, 25 parts), pure float4 loads.
// ---------------------------------------------------------------------------
__global__ __launch_bounds__(256) void k_jreg(
    const float* __restrict__ Jreg, const float* __restrict__ v_shaped,
    float* __restrict__ jpart) {
  int j = blockIdx.x, part = blockIdx.y, tid = threadIdx.x;
  const int SL = NV / NPART;  // 4000
  int v0 = part * SL;
  const float4* w4 = (const float4*)(Jreg + (size_t)j * NV + v0);
  const float4* s4 = (const float4*)(v_shaped + (size_t)3 * v0);
  float s0 = 0.f, s1 = 0.f, s2 = 0.f;
  for (int i4 = tid; i4 < SL / 4; i4 += 256) {
    float4 w = w4[i4];
    float4 A = s4[3 * i4 + 0];
    float4 B = s4[3 * i4 + 1];
    float4 C = s4[3 * i4 + 2];
    s0 += w.x * A.x + w.y * A.w + w.z * B.z + w.w * C.y;
    s1 += w.x * A.y + w.y * B.x + w.z * B.w + w.w * C.z;
    s2 += w.x * A.z + w.y * B.y + w.z * C.x + w.w * C.w;
  }
  __shared__ float red[256][3];
  red[tid][0] = s0; red[tid][1] = s1; red[tid][2] = s2;
  __syncthreads();
  for (int off = 128; off > 0; off >>= 1) {
    if (tid < off) {
      red[tid][0] += red[tid + off][0];
      red[tid][1] += red[tid + off][1];
      red[tid][2] += red[tid + off][2];
    }
    __syncthreads();
  }
  if (tid < 3) jpart[(part * NJ + j) * 3 + tid] = red[0][tid];
}

// ---------------------------------------------------------------------------
// K3: single block: finalize J, rodrigues, FK chain, rel matrices, lrotmin
// ---------------------------------------------------------------------------
__global__ __launch_bounds__(64) void k_fk(
    const float* __restrict__ pose, const float* __restrict__ jpart,
    float* __restrict__ lrot, float* __restrict__ rel) {
  __shared__ float J[NJ][3];
  __shared__ float R[NJ][9];
  __shared__ float G[NJ][12];
  int tid = threadIdx.x;
  if (tid < NJ) {
    for (int k = 0; k < 3; ++k) {
      float a = 0.f;
      for (int part = 0; part < NPART; ++part) a += jpart[(part * NJ + tid) * 3 + k];
      J[tid][k] = a;
    }
    float rx = pose[tid * 3 + 0], ry = pose[tid * 3 + 1], rz = pose[tid * 3 + 2];
    float tx = rx + 1e-8f, ty = ry + 1e-8f, tz = rz + 1e-8f;
    float theta = sqrtf(tx * tx + ty * ty + tz * tz);
    float x = rx / theta, y = ry / theta, z = rz / theta;
    float c = cosf(theta), s = sinf(theta), C = 1.f - c;
    float* Rr = R[tid];
    Rr[0] = c + C * x * x;     Rr[1] = C * x * y - s * z; Rr[2] = C * x * z + s * y;
    Rr[3] = C * x * y + s * z; Rr[4] = c + C * y * y;     Rr[5] = C * y * z - s * x;
    Rr[6] = C * x * z - s * y; Rr[7] = C * y * z + s * x; Rr[8] = c + C * z * z;
    if (tid >= 1) {
      #pragma unroll
      for (int e = 0; e < 9; ++e) {
        float id = (e == 0 || e == 4 || e == 8) ? 1.f : 0.f;
        lrot[(tid - 1) * 9 + e] = Rr[e] - id;
      }
    }
  }
  __syncthreads();
  if (tid == 0) {
    const int par[NJ] = {-1,0,0,0,1,2,3,4,5,6,7,8,9,9,9,12,13,14,16,17,18,19,20,21};
    for (int a = 0; a < 3; ++a) {
      for (int b = 0; b < 3; ++b) G[0][a * 4 + b] = R[0][a * 3 + b];
      G[0][a * 4 + 3] = J[0][a];
    }
    for (int i = 1; i < NJ; ++i) {
      int p = par[i];
      float t0 = J[i][0] - J[p][0], t1 = J[i][1] - J[p][1], t2 = J[i][2] - J[p][2];
      for (int a = 0; a < 3; ++a) {
        float g0 = G[p][a * 4 + 0], g1 = G[p][a * 4 + 1], g2 = G[p][a * 4 + 2];
        for (int b = 0; b < 3; ++b)
          G[i][a * 4 + b] = g0 * R[i][0 * 3 + b] + g1 * R[i][1 * 3 + b] + g2 * R[i][2 * 3 + b];
        G[i][a * 4 + 3] = G[p][a * 4 + 3] + g0 * t0 + g1 * t1 + g2 * t2;
      }
    }
  }
  __syncthreads();
  if (tid < NJ) {
    for (int a = 0; a < 3; ++a) {
      float corr = G[tid][a * 4 + 0] * J[tid][0] + G[tid][a * 4 + 1] * J[tid][1] +
                   G[tid][a * 4 + 2] * J[tid][2];
      rel[tid * 12 + a * 4 + 0] = G[tid][a * 4 + 0];
      rel[tid * 12 + a * 4 + 1] = G[tid][a * 4 + 1];
      rel[tid * 12 + a * 4 + 2] = G[tid][a * 4 + 2];
      rel[tid * 12 + a * 4 + 3] = G[tid][a * 4 + 3] - corr;
    }
  }
}

// ---------------------------------------------------------------------------
// Stage one 8-vertex posedirs tile (1242 float4) into LDS via DMA.
// All 4 waves issue exactly 5 global_load_lds -> uniform vmcnt accounting.
// ---------------------------------------------------------------------------
__device__ __forceinline__ void stage_tile(float4* dst, const float4* src, int tid) {
  #pragma unroll
  for (int r = 0; r < 5; ++r) {
    int i4 = r * 256 + tid;
    if (i4 < TF4) {
      __builtin_amdgcn_global_load_lds(
          (const __attribute__((address_space(1))) void*)(src + i4),
          (__attribute__((address_space(3))) void*)(dst + r * 256 + (tid & 192)),
          16, 0, 0);
    }
  }
}

// ---------------------------------------------------------------------------
// K4: fused pose-blend + LBS (R6 base). ONE change: the per-iter scalars
// (pvl, wj) are prefetched one round AHEAD and the wait is vmcnt(7).
// Steady state, per-wave outstanding order entering round i:
//   [P_i(2), S_{i-1}(5)]  (left by round i-1's vmcnt(7))
// round i issues P_{i+1}(2), S_i(5) -> 14 outstanding; vmcnt(7) drains
// exactly P_i + S_{i-1} -- both issued a FULL round (~5us) earlier, so the
// wait never stalls; compute touches zero fresh VMEM.
// ---------------------------------------------------------------------------
__global__ __launch_bounds__(256, 4) void k_fused(
    const float* __restrict__ posedirs, const float* __restrict__ wgt,
    const float* __restrict__ lrot, const float* __restrict__ rel,
    const float* __restrict__ scale, const float* __restrict__ trans,
    float* __restrict__ vbuf) {
  __shared__ float4 tile[2][TF4];
  int tid = threadIdx.x, b = blockIdx.x;
  int wid = tid >> 6, lane = tid & 63, half = lane >> 5, lj = lane & 31;
  const float4* pd4 = (const float4*)posedirs;

  // prologue: P_0 scalars, then stage tile b
  int vv0 = b * VPB + (wid << 1) + half;
  float pvl = (lj < 3) ? vbuf[(size_t)3 * vv0 + lj] : 0.f;
  float wj  = (lj < NJ) ? wgt[(size_t)vv0 * NJ + lj] : 0.f;
  __builtin_amdgcn_sched_barrier(0);
  stage_tile(&tile[0][0], pd4 + (size_t)b * TF4, tid);

  // per-lane constants (compiler inserts its own waits for these; our asm
  // waits only tighten the real outstanding count, so they stay correct)
  float llr[7];
  #pragma unroll
  for (int e = 0; e < 7; ++e) {
    int p = lj + 32 * e;
    llr[e] = (p < NP) ? lrot[p] : 0.f;
  }
  float rlq[12];
  #pragma unroll
  for (int e = 0; e < 12; ++e) rlq[e] = (lj < NJ) ? rel[lj * 12 + e] : 0.f;
  float sc = scale[0];
  float tr = (lj < 3) ? trans[lj] : 0.f;

  int nt = (NTILES - 1 - b) / GRIDF + 1;
  // drain P_0 + stage(tile b) (oldest); constants may still be in flight
  asm volatile("s_waitcnt vmcnt(5)" ::: "memory");
  __syncthreads();

  for (int it = 0; it < nt; ++it) {
    int cur = it & 1;
    // prefetch NEXT round's scalars (clamped on last iter)
    int tnE = b + (it + 1) * GRIDF;
    if (tnE >= NTILES) tnE = NTILES - 1;
    int vvn = tnE * VPB + (wid << 1) + half;
    float pvl_n = (lj < 3) ? vbuf[(size_t)3 * vvn + lj] : 0.f;
    float wj_n  = (lj < NJ) ? wgt[(size_t)vvn * NJ + lj] : 0.f;
    __builtin_amdgcn_sched_barrier(0);
    // stage tile it+1 (dummy clamped on last iter)
    stage_tile(&tile[cur ^ 1][0], pd4 + (size_t)tnE * TF4, tid);
    asm volatile("s_waitcnt vmcnt(7)" ::: "memory");
    __builtin_amdgcn_sched_barrier(0);
    __builtin_amdgcn_s_barrier();
    __builtin_amdgcn_sched_barrier(0);

    int vv = (b + it * GRIDF) * VPB + (wid << 1) + half;
    const float* row = (const float*)&tile[cur][0] + ((wid << 1) + half) * (3 * NP);
    float a0 = 0.f, a1 = 0.f, a2 = 0.f;
    #pragma unroll
    for (int e = 0; e < 7; ++e) {
      int p = lj + 32 * e;
      if (p < NP) {
        float l = llr[e];
        a0 += row[p] * l;
        a1 += row[NP + p] * l;
        a2 += row[2 * NP + p] * l;
      }
    }
    #pragma unroll
    for (int off = 16; off > 0; off >>= 1) {
      a0 += __shfl_xor(a0, off);
      a1 += __shfl_xor(a1, off);
      a2 += __shfl_xor(a2, off);
    }
    int gb = lane & 32;
    float p0 = __shfl(pvl, gb + 0) + a0;
    float p1 = __shfl(pvl, gb + 1) + a1;
    float p2 = __shfl(pvl, gb + 2) + a2;
    float q0 = rlq[0] * p0 + rlq[1] * p1 + rlq[2]  * p2 + rlq[3];
    float q1 = rlq[4] * p0 + rlq[5] * p1 + rlq[6]  * p2 + rlq[7];
    float q2 = rlq[8] * p0 + rlq[9] * p1 + rlq[10] * p2 + rlq[11];
    float r0 = wj * q0, r1 = wj * q1, r2 = wj * q2;
    #pragma unroll
    for (int off = 16; off > 0; off >>= 1) {
      r0 += __shfl_xor(r0, off);
      r1 += __shfl_xor(r1, off);
      r2 += __shfl_xor(r2, off);
    }
    if (lj < 3) {
      float oo = (lj == 0) ? r0 : (lj == 1) ? r1 : r2;
      vbuf[(size_t)3 * vv + lj] = oo * sc + tr;
    }
    __builtin_amdgcn_sched_barrier(0);
    __builtin_amdgcn_s_barrier();
    __builtin_amdgcn_sched_barrier(0);

    pvl = pvl_n; wj = wj_n;
  }
  asm volatile("s_waitcnt vmcnt(0)" ::: "memory");  // drain tail dummies
}

extern "C" void kernel_launch(void* const* d_in, const int* in_sizes, int n_in,
                              void* d_out, int out_size, void* d_ws, size_t ws_size,
                              hipStream_t stream) {
  const float* betas      = (const float*)d_in[0];
  const float* pose       = (const float*)d_in[1];
  const float* scale      = (const float*)d_in[2];
  const float* trans      = (const float*)d_in[3];
  const float* v_template = (const float*)d_in[4];
  const float* shapedirs  = (const float*)d_in[5];
  const float* posedirs   = (const float*)d_in[6];
  const float* Jreg       = (const float*)d_in[7];
  const float* weights    = (const float*)d_in[8];
  float* out = (float*)d_out;
  float* ws  = (float*)d_ws;

  float* jpart = ws;          // 25*24*3 = 1800 floats
  float* lrot  = ws + 1800;   // 207 floats
  float* rel   = ws + 2048;   // 288 floats

  k_shape<<<(3 * NV + 255) / 256, 256, 0, stream>>>(betas, v_template, shapedirs, out);
  k_jreg<<<dim3(NJ, NPART), 256, 0, stream>>>(Jreg, out, jpart);
  k_fk<<<1, 64, 0, stream>>>(pose, jpart, lrot, rel);
  k_fused<<<GRIDF, 256, 0, stream>>>(posedirs, weights, lrot, rel, scale, trans, out);
}

// Round 14
// 61.621 us; speedup vs baseline: 1.4009x; 1.0950x over previous
//
#include <hip/hip_runtime.h>

#define NV 100000
#define NJ 24
#define NP 207
#define NPART 25
#define VPB 8
#define NTILES (NV / VPB)      // 12500
#define TF4 1242               // float4 per tile = VPB*621/4
#define GRIDF 1024

// ---------------------------------------------------------------------------
// K1: v_shaped = v_template + shapedirs @ betas. 2 rows per thread ->
// 5 aligned float4 + 1 float2 in, 1 float2 out. 150000 threads.
// ---------------------------------------------------------------------------
__global__ __launch_bounds__(256) void k_shape(
    const float* __restrict__ betas, const float* __restrict__ v_template,
    const float* __restrict__ shapedirs, float* __restrict__ v_shaped) {
  __shared__ float sb[10];
  if (threadIdx.x < 10) sb[threadIdx.x] = betas[threadIdx.x];
  __syncthreads();
  int t = blockIdx.x * 256 + threadIdx.x;  // row-pair index
  if (t >= 3 * NV / 2) return;
  const float4* sd4 = (const float4*)(shapedirs + (size_t)t * 20);
  float4 f0 = sd4[0], f1 = sd4[1], f2 = sd4[2], f3 = sd4[3], f4v = sd4[4];
  float2 vt = ((const float2*)v_template)[t];
  float a = vt.x
          + f0.x * sb[0] + f0.y * sb[1] + f0.z * sb[2] + f0.w * sb[3]
          + f1.x * sb[4] + f1.y * sb[5] + f1.z * sb[6] + f1.w * sb[7]
          + f2.x * sb[8] + f2.y * sb[9];
  float b = vt.y
          + f2.z * sb[0] + f2.w * sb[1]
          + f3.x * sb[2] + f3.y * sb[3] + f3.z * sb[4] + f3.w * sb[5]
          + f4v.x * sb[6] + f4v.y * sb[7] + f4v.z * sb[8] + f4v.w * sb[9];
  ((float2*)v_shaped)[t] = make_float2(a, b);
}

// ---------------------------------------------------------------------------
// K2: J partials. grid = (24 joints, 25 parts), pure float4 loads.
// Writes TRANSPOSED jpT[(j*3+k)*32 + part] for contiguous consumer reads.
// ---------------------------------------------------------------------------
__global__ __launch_bounds__(256) void k_jreg(
    const float* __restrict__ Jreg, const float* __restrict__ v_shaped,
    float* __restrict__ jpT) {
  int j = blockIdx.x, part = blockIdx.y, tid = threadIdx.x;
  const int SL = NV / NPART;  // 4000
  int v0 = part * SL;
  const float4* w4 = (const float4*)(Jreg + (size_t)j * NV + v0);
  const float4* s4 = (const float4*)(v_shaped + (size_t)3 * v0);
  float s0 = 0.f, s1 = 0.f, s2 = 0.f;
  for (int i4 = tid; i4 < SL / 4; i4 += 256) {
    float4 w = w4[i4];
    float4 A = s4[3 * i4 + 0];
    float4 B = s4[3 * i4 + 1];
    float4 C = s4[3 * i4 + 2];
    s0 += w.x * A.x + w.y * A.w + w.z * B.z + w.w * C.y;
    s1 += w.x * A.y + w.y * B.x + w.z * B.w + w.w * C.z;
    s2 += w.x * A.z + w.y * B.y + w.z * C.x + w.w * C.w;
  }
  __shared__ float red[256][3];
  red[tid][0] = s0; red[tid][1] = s1; red[tid][2] = s2;
  __syncthreads();
  for (int off = 128; off > 0; off >>= 1) {
    if (tid < off) {
      red[tid][0] += red[tid + off][0];
      red[tid][1] += red[tid + off][1];
      red[tid][2] += red[tid + off][2];
    }
    __syncthreads();
  }
  if (tid < 3) jpT[(j * 3 + tid) * 32 + part] = red[0][tid];
}

// ---------------------------------------------------------------------------
// Stage one 8-vertex posedirs tile (1242 float4) into LDS via DMA.
// All 4 waves issue exactly 5 global_load_lds -> uniform vmcnt accounting.
// ---------------------------------------------------------------------------
__device__ __forceinline__ void stage_tile(float4* dst, const float4* src, int tid) {
  #pragma unroll
  for (int r = 0; r < 5; ++r) {
    int i4 = r * 256 + tid;
    if (i4 < TF4) {
      __builtin_amdgcn_global_load_lds(
          (const __attribute__((address_space(1))) void*)(src + i4),
          (__attribute__((address_space(3))) void*)(dst + r * 256 + (tid & 192)),
          16, 0, 0);
    }
  }
}

// ---------------------------------------------------------------------------
// K3: fused FK + pose-blend + LBS. R13's loop verbatim; FK computed
// REDUNDANTLY per block in the prologue (overlapping tile-0 DMA):
//  - 72 threads reduce jpT (25 contiguous floats each)
//  - 24-lane rodrigues -> R, lrs(lrotmin)
//  - 3-lane ROW-PARALLEL chain (rows of G_i = G_p * A_i are independent)
//  - 24-lane rel
// All FK scratch aliases tile[1] (only staged in round 0, after the
// pre-loop sync; llr/rlq are register-resident by then).
// ---------------------------------------------------------------------------
__global__ __launch_bounds__(256, 4) void k_fused(
    const float* __restrict__ posedirs, const float* __restrict__ wgt,
    const float* __restrict__ pose, const float* __restrict__ jpT,
    const float* __restrict__ scale, const float* __restrict__ trans,
    float* __restrict__ vbuf) {
  __shared__ float4 tile[2][TF4];
  int tid = threadIdx.x, b = blockIdx.x;
  int wid = tid >> 6, lane = tid & 63, half = lane >> 5, lj = lane & 31;
  const float4* pd4 = (const float4*)posedirs;

  // P_0 scalars first, then prologue DMA of tile b
  int vv0 = b * VPB + (wid << 1) + half;
  float pvl = (lj < 3) ? vbuf[(size_t)3 * vv0 + lj] : 0.f;
  float wj  = (lj < NJ) ? wgt[(size_t)vv0 * NJ + lj] : 0.f;
  __builtin_amdgcn_sched_barrier(0);
  stage_tile(&tile[0][0], pd4 + (size_t)b * TF4, tid);

  // ---- FK in tile[1] scratch ----
  float* fkJ  = (float*)&tile[1][0];   // [24*3]
  float* fkR  = fkJ + 72;              // [24*9]
  float* fkG  = fkJ + 288;             // [24*12]
  float* lrs  = fkJ + 576;             // [207]
  float* relS = fkJ + 784;             // [24*12]
  if (tid < NJ * 3) {
    const float* src = jpT + tid * 32;
    float a = 0.f;
    #pragma unroll
    for (int i = 0; i < NPART; ++i) a += src[i];
    fkJ[tid] = a;
  }
  if (tid < NJ) {
    float rx = pose[tid * 3 + 0], ry = pose[tid * 3 + 1], rz = pose[tid * 3 + 2];
    float tx = rx + 1e-8f, ty = ry + 1e-8f, tz = rz + 1e-8f;
    float theta = sqrtf(tx * tx + ty * ty + tz * tz);
    float x = rx / theta, y = ry / theta, z = rz / theta;
    float c = cosf(theta), s = sinf(theta), C = 1.f - c;
    float Rr[9];
    Rr[0] = c + C * x * x;     Rr[1] = C * x * y - s * z; Rr[2] = C * x * z + s * y;
    Rr[3] = C * x * y + s * z; Rr[4] = c + C * y * y;     Rr[5] = C * y * z - s * x;
    Rr[6] = C * x * z - s * y; Rr[7] = C * y * z + s * x; Rr[8] = c + C * z * z;
    #pragma unroll
    for (int e = 0; e < 9; ++e) fkR[tid * 9 + e] = Rr[e];
    if (tid >= 1) {
      #pragma unroll
      for (int e = 0; e < 9; ++e) {
        float id = (e == 0 || e == 4 || e == 8) ? 1.f : 0.f;
        lrs[(tid - 1) * 9 + e] = Rr[e] - id;
      }
    }
  }
  __syncthreads();
  if (tid < 3) {  // row-parallel chain: lane a owns row a of all G_i
    const int par[NJ] = {-1,0,0,0,1,2,3,4,5,6,7,8,9,9,9,12,13,14,16,17,18,19,20,21};
    int a = tid;
    fkG[a * 4 + 0] = fkR[a * 3 + 0];
    fkG[a * 4 + 1] = fkR[a * 3 + 1];
    fkG[a * 4 + 2] = fkR[a * 3 + 2];
    fkG[a * 4 + 3] = fkJ[a];
    #pragma unroll
    for (int i = 1; i < NJ; ++i) {
      int p = par[i];
      float t0 = fkJ[i * 3 + 0] - fkJ[p * 3 + 0];
      float t1 = fkJ[i * 3 + 1] - fkJ[p * 3 + 1];
      float t2 = fkJ[i * 3 + 2] - fkJ[p * 3 + 2];
      float g0 = fkG[p * 12 + a * 4 + 0], g1 = fkG[p * 12 + a * 4 + 1];
      float g2 = fkG[p * 12 + a * 4 + 2], g3 = fkG[p * 12 + a * 4 + 3];
      fkG[i * 12 + a * 4 + 0] = g0 * fkR[i * 9 + 0] + g1 * fkR[i * 9 + 3] + g2 * fkR[i * 9 + 6];
      fkG[i * 12 + a * 4 + 1] = g0 * fkR[i * 9 + 1] + g1 * fkR[i * 9 + 4] + g2 * fkR[i * 9 + 7];
      fkG[i * 12 + a * 4 + 2] = g0 * fkR[i * 9 + 2] + g1 * fkR[i * 9 + 5] + g2 * fkR[i * 9 + 8];
      fkG[i * 12 + a * 4 + 3] = g3 + g0 * t0 + g1 * t1 + g2 * t2;
    }
  }
  __syncthreads();
  if (tid < NJ) {
    #pragma unroll
    for (int a = 0; a < 3; ++a) {
      float corr = fkG[tid * 12 + a * 4 + 0] * fkJ[tid * 3 + 0] +
                   fkG[tid * 12 + a * 4 + 1] * fkJ[tid * 3 + 1] +
                   fkG[tid * 12 + a * 4 + 2] * fkJ[tid * 3 + 2];
      relS[tid * 12 + a * 4 + 0] = fkG[tid * 12 + a * 4 + 0];
      relS[tid * 12 + a * 4 + 1] = fkG[tid * 12 + a * 4 + 1];
      relS[tid * 12 + a * 4 + 2] = fkG[tid * 12 + a * 4 + 2];
      relS[tid * 12 + a * 4 + 3] = fkG[tid * 12 + a * 4 + 3] - corr;
    }
  }
  __syncthreads();

  // per-lane constants from LDS scratch (tile[1] dies after this sync)
  float llr[7];
  #pragma unroll
  for (int e = 0; e < 7; ++e) {
    int p = lj + 32 * e;
    llr[e] = (p < NP) ? lrs[p] : 0.f;
  }
  float rlq[12];
  #pragma unroll
  for (int e = 0; e < 12; ++e) rlq[e] = (lj < NJ) ? relS[lj * 12 + e] : 0.f;
  float sc = scale[0];
  float tr = (lj < 3) ? trans[lj] : 0.f;

  int nt = (NTILES - 1 - b) / GRIDF + 1;
  __syncthreads();  // all scratch reads done; round 0 may now stage tile[1]

  for (int it = 0; it < nt; ++it) {
    int cur = it & 1;
    // prefetch NEXT round's scalars (clamped on last iter)
    int tnE = b + (it + 1) * GRIDF;
    if (tnE >= NTILES) tnE = NTILES - 1;
    int vvn = tnE * VPB + (wid << 1) + half;
    float pvl_n = (lj < 3) ? vbuf[(size_t)3 * vvn + lj] : 0.f;
    float wj_n  = (lj < NJ) ? wgt[(size_t)vvn * NJ + lj] : 0.f;
    __builtin_amdgcn_sched_barrier(0);
    // stage tile it+1 (dummy clamped on last iter)
    stage_tile(&tile[cur ^ 1][0], pd4 + (size_t)tnE * TF4, tid);
    asm volatile("s_waitcnt vmcnt(7)" ::: "memory");
    __builtin_amdgcn_sched_barrier(0);
    __builtin_amdgcn_s_barrier();
    __builtin_amdgcn_sched_barrier(0);

    int vv = (b + it * GRIDF) * VPB + (wid << 1) + half;
    const float* row = (const float*)&tile[cur][0] + ((wid << 1) + half) * (3 * NP);
    float a0 = 0.f, a1 = 0.f, a2 = 0.f;
    #pragma unroll
    for (int e = 0; e < 7; ++e) {
      int p = lj + 32 * e;
      if (p < NP) {
        float l = llr[e];
        a0 += row[p] * l;
        a1 += row[NP + p] * l;
        a2 += row[2 * NP + p] * l;
      }
    }
    #pragma unroll
    for (int off = 16; off > 0; off >>= 1) {
      a0 += __shfl_xor(a0, off);
      a1 += __shfl_xor(a1, off);
      a2 += __shfl_xor(a2, off);
    }
    int gb = lane & 32;
    float p0 = __shfl(pvl, gb + 0) + a0;
    float p1 = __shfl(pvl, gb + 1) + a1;
    float p2 = __shfl(pvl, gb + 2) + a2;
    float q0 = rlq[0] * p0 + rlq[1] * p1 + rlq[2]  * p2 + rlq[3];
    float q1 = rlq[4] * p0 + rlq[5] * p1 + rlq[6]  * p2 + rlq[7];
    float q2 = rlq[8] * p0 + rlq[9] * p1 + rlq[10] * p2 + rlq[11];
    float r0 = wj * q0, r1 = wj * q1, r2 = wj * q2;
    #pragma unroll
    for (int off = 16; off > 0; off >>= 1) {
      r0 += __shfl_xor(r0, off);
      r1 += __shfl_xor(r1, off);
      r2 += __shfl_xor(r2, off);
    }
    if (lj < 3) {
      float oo = (lj == 0) ? r0 : (lj == 1) ? r1 : r2;
      vbuf[(size_t)3 * vv + lj] = oo * sc + tr;
    }
    __builtin_amdgcn_sched_barrier(0);
    __builtin_amdgcn_s_barrier();
    __builtin_amdgcn_sched_barrier(0);

    pvl = pvl_n; wj = wj_n;
  }
  asm volatile("s_waitcnt vmcnt(0)" ::: "memory");  // drain tail dummies
}

extern "C" void kernel_launch(void* const* d_in, const int* in_sizes, int n_in,
                              void* d_out, int out_size, void* d_ws, size_t ws_size,
                              hipStream_t stream) {
  const float* betas      = (const float*)d_in[0];
  const float* pose       = (const float*)d_in[1];
  const float* scale      = (const float*)d_in[2];
  const float* trans      = (const float*)d_in[3];
  const float* v_template = (const float*)d_in[4];
  const float* shapedirs  = (const float*)d_in[5];
  const float* posedirs   = (const float*)d_in[6];
  const float* Jreg       = (const float*)d_in[7];
  const float* weights    = (const float*)d_in[8];
  float* out = (float*)d_out;
  float* ws  = (float*)d_ws;

  float* jpT = ws;  // 72*32 = 2304 floats

  k_shape<<<(3 * NV / 2 + 255) / 256, 256, 0, stream>>>(betas, v_template, shapedirs, out);
  k_jreg<<<dim3(NJ, NPART), 256, 0, stream>>>(Jreg, out, jpT);
  k_fused<<<GRIDF, 256, 0, stream>>>(posedirs, weights, pose, jpT, scale, trans, out);
}

// Round 15
// 60.356 us; speedup vs baseline: 1.4302x; 1.0210x over previous
//
#include <hip/hip_runtime.h>

#define NV 100000
#define NJ 24
#define NP 207
#define NPART 25
#define NQUADS (NV / 4)        // 25000 4-vertex chunks
#define GRIDF 512
#define NWV (GRIDF * 4)        // 2048 waves

// ---------------------------------------------------------------------------
// K1: v_shaped = v_template + shapedirs @ betas. 2 rows per thread ->
// 5 aligned float4 + 1 float2 in, 1 float2 out. 150000 threads.
// ---------------------------------------------------------------------------
__global__ __launch_bounds__(256) void k_shape(
    const float* __restrict__ betas, const float* __restrict__ v_template,
    const float* __restrict__ shapedirs, float* __restrict__ v_shaped) {
  __shared__ float sb[10];
  if (threadIdx.x < 10) sb[threadIdx.x] = betas[threadIdx.x];
  __syncthreads();
  int t = blockIdx.x * 256 + threadIdx.x;  // row-pair index
  if (t >= 3 * NV / 2) return;
  const float4* sd4 = (const float4*)(shapedirs + (size_t)t * 20);
  float4 f0 = sd4[0], f1 = sd4[1], f2 = sd4[2], f3 = sd4[3], f4v = sd4[4];
  float2 vt = ((const float2*)v_template)[t];
  float a = vt.x
          + f0.x * sb[0] + f0.y * sb[1] + f0.z * sb[2] + f0.w * sb[3]
          + f1.x * sb[4] + f1.y * sb[5] + f1.z * sb[6] + f1.w * sb[7]
          + f2.x * sb[8] + f2.y * sb[9];
  float b = vt.y
          + f2.z * sb[0] + f2.w * sb[1]
          + f3.x * sb[2] + f3.y * sb[3] + f3.z * sb[4] + f3.w * sb[5]
          + f4v.x * sb[6] + f4v.y * sb[7] + f4v.z * sb[8] + f4v.w * sb[9];
  ((float2*)v_shaped)[t] = make_float2(a, b);
}

// ---------------------------------------------------------------------------
// K2: J partials. grid = (24 joints, 25 parts), pure float4 loads.
// Writes TRANSPOSED jpT[(j*3+k)*32 + part] for contiguous consumer reads.
// ---------------------------------------------------------------------------
__global__ __launch_bounds__(256) void k_jreg(
    const float* __restrict__ Jreg, const float* __restrict__ v_shaped,
    float* __restrict__ jpT) {
  int j = blockIdx.x, part = blockIdx.y, tid = threadIdx.x;
  const int SL = NV / NPART;  // 4000
  int v0 = part * SL;
  const float4* w4 = (const float4*)(Jreg + (size_t)j * NV + v0);
  const float4* s4 = (const float4*)(v_shaped + (size_t)3 * v0);
  float s0 = 0.f, s1 = 0.f, s2 = 0.f;
  for (int i4 = tid; i4 < SL / 4; i4 += 256) {
    float4 w = w4[i4];
    float4 A = s4[3 * i4 + 0];
    float4 B = s4[3 * i4 + 1];
    float4 C = s4[3 * i4 + 2];
    s0 += w.x * A.x + w.y * A.w + w.z * B.z + w.w * C.y;
    s1 += w.x * A.y + w.y * B.x + w.z * B.w + w.w * C.z;
    s2 += w.x * A.z + w.y * B.y + w.z * C.x + w.w * C.w;
  }
  __shared__ float red[256][3];
  red[tid][0] = s0; red[tid][1] = s1; red[tid][2] = s2;
  __syncthreads();
  for (int off = 128; off > 0; off >>= 1) {
    if (tid < off) {
      red[tid][0] += red[tid + off][0];
      red[tid][1] += red[tid + off][1];
      red[tid][2] += red[tid + off][2];
    }
    __syncthreads();
  }
  if (tid < 3) jpT[(j * 3 + tid) * 32 + part] = red[0][tid];
}

// ---------------------------------------------------------------------------
// Stage one 4-vertex posedirs chunk (621 float4, padded dest 640) into this
// wave's LDS buffer. 10 per-wave global_load_lds; src clamped (pad absorbs
// dup writes); vmcnt is per-wave so no cross-wave uniformity needed.
// ---------------------------------------------------------------------------
__device__ __forceinline__ void stage_quad(float4* dst, const float4* src, int lane) {
  #pragma unroll
  for (int r = 0; r < 10; ++r) {
    int i4 = r * 64 + lane;
    int i4c = (i4 < 621) ? i4 : 620;
    __builtin_amdgcn_global_load_lds(
        (const __attribute__((address_space(1))) void*)(src + i4c),
        (__attribute__((address_space(3))) void*)(dst + r * 64),
        16, 0, 0);
  }
}

// ---------------------------------------------------------------------------
// K3: fused FK + pose-blend + LBS, BARRIER-FREE per-wave pipeline.
// Each wave owns buf[wid][2][640] (double-buffered 4-vertex chunks).
// Per iter: prefetch next scalars (4) + stage next chunk (10) -> vmcnt(14)
// drains exactly the PREVIOUS iter's 14 (a full iteration old -> no stall)
// -> compute 2x 32-lane passes. No s_barrier in the loop; waves fully
// decoupled. FK prologue (block-synced) aliases buf[0][1].
// ---------------------------------------------------------------------------
__global__ __launch_bounds__(256, 2) void k_fused(
    const float* __restrict__ posedirs, const float* __restrict__ wgt,
    const float* __restrict__ pose, const float* __restrict__ jpT,
    const float* __restrict__ scale, const float* __restrict__ trans,
    float* __restrict__ vbuf) {
  __shared__ float4 buf[4][2][640];   // 81920 B = 2 blocks/CU exactly
  int tid = threadIdx.x, b = blockIdx.x;
  int wid = tid >> 6, lane = tid & 63, half = lane >> 5, lj = lane & 31;
  int W = b * 4 + wid;                // wave id 0..2047
  const float4* pd4 = (const float4*)posedirs;

  // P_0 scalars + S_0 stage for quad W
  int q0 = W;
  float pvl0 = (lj < 3) ? vbuf[(size_t)3 * (q0 * 4 + half) + lj] : 0.f;
  float wj0  = (lj < NJ) ? wgt[(size_t)(q0 * 4 + half) * NJ + lj] : 0.f;
  float pvl1 = (lj < 3) ? vbuf[(size_t)3 * (q0 * 4 + 2 + half) + lj] : 0.f;
  float wj1  = (lj < NJ) ? wgt[(size_t)(q0 * 4 + 2 + half) * NJ + lj] : 0.f;
  __builtin_amdgcn_sched_barrier(0);
  stage_quad(&buf[wid][0][0], pd4 + (size_t)q0 * 621, lane);

  // ---- FK in buf[0][1] scratch (dead before any wave stages into it) ----
  float* fkJ  = (float*)&buf[0][1][0];  // [24*3]
  float* fkR  = fkJ + 72;               // [24*9]
  float* fkG  = fkJ + 288;              // [24*12]
  float* lrs  = fkJ + 576;              // [207]
  float* relS = fkJ + 784;              // [24*12]
  if (tid < NJ * 3) {
    const float* src = jpT + tid * 32;
    float a = 0.f;
    #pragma unroll
    for (int i = 0; i < NPART; ++i) a += src[i];
    fkJ[tid] = a;
  }
  if (tid < NJ) {
    float rx = pose[tid * 3 + 0], ry = pose[tid * 3 + 1], rz = pose[tid * 3 + 2];
    float tx = rx + 1e-8f, ty = ry + 1e-8f, tz = rz + 1e-8f;
    float theta = sqrtf(tx * tx + ty * ty + tz * tz);
    float x = rx / theta, y = ry / theta, z = rz / theta;
    float c = cosf(theta), s = sinf(theta), C = 1.f - c;
    float Rr[9];
    Rr[0] = c + C * x * x;     Rr[1] = C * x * y - s * z; Rr[2] = C * x * z + s * y;
    Rr[3] = C * x * y + s * z; Rr[4] = c + C * y * y;     Rr[5] = C * y * z - s * x;
    Rr[6] = C * x * z - s * y; Rr[7] = C * y * z + s * x; Rr[8] = c + C * z * z;
    #pragma unroll
    for (int e = 0; e < 9; ++e) fkR[tid * 9 + e] = Rr[e];
    if (tid >= 1) {
      #pragma unroll
      for (int e = 0; e < 9; ++e) {
        float id = (e == 0 || e == 4 || e == 8) ? 1.f : 0.f;
        lrs[(tid - 1) * 9 + e] = Rr[e] - id;
      }
    }
  }
  __syncthreads();
  if (tid < 3) {  // row-parallel chain: lane a owns row a of all G_i
    const int par[NJ] = {-1,0,0,0,1,2,3,4,5,6,7,8,9,9,9,12,13,14,16,17,18,19,20,21};
    int a = tid;
    fkG[a * 4 + 0] = fkR[a * 3 + 0];
    fkG[a * 4 + 1] = fkR[a * 3 + 1];
    fkG[a * 4 + 2] = fkR[a * 3 + 2];
    fkG[a * 4 + 3] = fkJ[a];
    #pragma unroll
    for (int i = 1; i < NJ; ++i) {
      int p = par[i];
      float t0 = fkJ[i * 3 + 0] - fkJ[p * 3 + 0];
      float t1 = fkJ[i * 3 + 1] - fkJ[p * 3 + 1];
      float t2 = fkJ[i * 3 + 2] - fkJ[p * 3 + 2];
      float g0 = fkG[p * 12 + a * 4 + 0], g1 = fkG[p * 12 + a * 4 + 1];
      float g2 = fkG[p * 12 + a * 4 + 2], g3 = fkG[p * 12 + a * 4 + 3];
      fkG[i * 12 + a * 4 + 0] = g0 * fkR[i * 9 + 0] + g1 * fkR[i * 9 + 3] + g2 * fkR[i * 9 + 6];
      fkG[i * 12 + a * 4 + 1] = g0 * fkR[i * 9 + 1] + g1 * fkR[i * 9 + 4] + g2 * fkR[i * 9 + 7];
      fkG[i * 12 + a * 4 + 2] = g0 * fkR[i * 9 + 2] + g1 * fkR[i * 9 + 5] + g2 * fkR[i * 9 + 8];
      fkG[i * 12 + a * 4 + 3] = g3 + g0 * t0 + g1 * t1 + g2 * t2;
    }
  }
  __syncthreads();
  if (tid < NJ) {
    #pragma unroll
    for (int a = 0; a < 3; ++a) {
      float corr = fkG[tid * 12 + a * 4 + 0] * fkJ[tid * 3 + 0] +
                   fkG[tid * 12 + a * 4 + 1] * fkJ[tid * 3 + 1] +
                   fkG[tid * 12 + a * 4 + 2] * fkJ[tid * 3 + 2];
      relS[tid * 12 + a * 4 + 0] = fkG[tid * 12 + a * 4 + 0];
      relS[tid * 12 + a * 4 + 1] = fkG[tid * 12 + a * 4 + 1];
      relS[tid * 12 + a * 4 + 2] = fkG[tid * 12 + a * 4 + 2];
      relS[tid * 12 + a * 4 + 3] = fkG[tid * 12 + a * 4 + 3] - corr;
    }
  }
  __syncthreads();

  float llr[7];
  #pragma unroll
  for (int e = 0; e < 7; ++e) {
    int p = lj + 32 * e;
    llr[e] = (p < NP) ? lrs[p] : 0.f;
  }
  float rlq[12];
  #pragma unroll
  for (int e = 0; e < 12; ++e) rlq[e] = (lj < NJ) ? relS[lj * 12 + e] : 0.f;
  float sc = scale[0];
  float tr = (lj < 3) ? trans[lj] : 0.f;

  __syncthreads();  // scratch reads done; buf[0][1] may be staged from now on
  asm volatile("s_waitcnt vmcnt(0)" ::: "memory");  // clean per-wave base

  int nt = (NQUADS - 1 - W) / NWV + 1;  // per-wave; no uniformity needed
  for (int it = 0; it < nt; ++it) {
    int cur = it & 1;
    int qn = W + (it + 1) * NWV;
    if (qn >= NQUADS) qn = NQUADS - 1;  // dummy on last iter
    float pvl0_n = (lj < 3) ? vbuf[(size_t)3 * (qn * 4 + half) + lj] : 0.f;
    float wj0_n  = (lj < NJ) ? wgt[(size_t)(qn * 4 + half) * NJ + lj] : 0.f;
    float pvl1_n = (lj < 3) ? vbuf[(size_t)3 * (qn * 4 + 2 + half) + lj] : 0.f;
    float wj1_n  = (lj < NJ) ? wgt[(size_t)(qn * 4 + 2 + half) * NJ + lj] : 0.f;
    __builtin_amdgcn_sched_barrier(0);
    stage_quad(&buf[wid][cur ^ 1][0], pd4 + (size_t)qn * 621, lane);
    asm volatile("s_waitcnt vmcnt(14)" ::: "memory");
    __builtin_amdgcn_sched_barrier(0);

    int q = W + it * NWV;
    const float* chunk = (const float*)&buf[wid][cur][0];
    #pragma unroll
    for (int h = 0; h < 2; ++h) {
      int vv = q * 4 + 2 * h + half;
      const float* row = chunk + (2 * h + half) * (3 * NP);
      float pvl = h ? pvl1 : pvl0;
      float wj  = h ? wj1 : wj0;
      float a0 = 0.f, a1 = 0.f, a2 = 0.f;
      #pragma unroll
      for (int e = 0; e < 7; ++e) {
        int p = lj + 32 * e;
        if (p < NP) {
          float l = llr[e];
          a0 += row[p] * l;
          a1 += row[NP + p] * l;
          a2 += row[2 * NP + p] * l;
        }
      }
      #pragma unroll
      for (int off = 16; off > 0; off >>= 1) {
        a0 += __shfl_xor(a0, off);
        a1 += __shfl_xor(a1, off);
        a2 += __shfl_xor(a2, off);
      }
      int gb = lane & 32;
      float p0 = __shfl(pvl, gb + 0) + a0;
      float p1 = __shfl(pvl, gb + 1) + a1;
      float p2 = __shfl(pvl, gb + 2) + a2;
      float q0v = rlq[0] * p0 + rlq[1] * p1 + rlq[2]  * p2 + rlq[3];
      float q1v = rlq[4] * p0 + rlq[5] * p1 + rlq[6]  * p2 + rlq[7];
      float q2v = rlq[8] * p0 + rlq[9] * p1 + rlq[10] * p2 + rlq[11];
      float r0 = wj * q0v, r1 = wj * q1v, r2 = wj * q2v;
      #pragma unroll
      for (int off = 16; off > 0; off >>= 1) {
        r0 += __shfl_xor(r0, off);
        r1 += __shfl_xor(r1, off);
        r2 += __shfl_xor(r2, off);
      }
      if (lj < 3) {
        float oo = (lj == 0) ? r0 : (lj == 1) ? r1 : r2;
        vbuf[(size_t)3 * vv + lj] = oo * sc + tr;
      }
    }
    pvl0 = pvl0_n; wj0 = wj0_n; pvl1 = pvl1_n; wj1 = wj1_n;
  }
  asm volatile("s_waitcnt vmcnt(0)" ::: "memory");  // drain tail dummies
}

extern "C" void kernel_launch(void* const* d_in, const int* in_sizes, int n_in,
                              void* d_out, int out_size, void* d_ws, size_t ws_size,
                              hipStream_t stream) {
  const float* betas      = (const float*)d_in[0];
  const float* pose       = (const float*)d_in[1];
  const float* scale      = (const float*)d_in[2];
  const float* trans      = (const float*)d_in[3];
  const float* v_template = (const float*)d_in[4];
  const float* shapedirs  = (const float*)d_in[5];
  const float* posedirs   = (const float*)d_in[6];
  const float* Jreg       = (const float*)d_in[7];
  const float* weights    = (const float*)d_in[8];
  float* out = (float*)d_out;
  float* ws  = (float*)d_ws;

  float* jpT = ws;  // 72*32 = 2304 floats

  k_shape<<<(3 * NV / 2 + 255) / 256, 256, 0, stream>>>(betas, v_template, shapedirs, out);
  k_jreg<<<dim3(NJ, NPART), 256, 0, stream>>>(Jreg, out, jpT);
  k_fused<<<GRIDF, 256, 0, stream>>>(posedirs, weights, pose, jpT, scale, trans, out);
}

// Round 16
// 59.795 us; speedup vs baseline: 1.4437x; 1.0094x over previous
//
#include <hip/hip_runtime.h>

#define NV 100000
#define NJ 24
#define NP 207
#define NPART 25
#define NQUADS (NV / 4)        // 25000 4-vertex chunks
#define GRIDF 512
#define NWV (GRIDF * 4)        // 2048 waves

// ---------------------------------------------------------------------------
// DPP 32-lane-group sum: row_shr 1/2/4/8 + row_bcast15 (VALU pipe, not LDS).
// bound_ctrl=1 -> out-of-range lanes contribute 0. After this, lane 31 holds
// sum(lanes 0..31) and lane 63 holds sum(lanes 32..63).
// ---------------------------------------------------------------------------
__device__ __forceinline__ float dpp_red32(float x) {
  x += __int_as_float(__builtin_amdgcn_update_dpp(0, __float_as_int(x), 0x111, 0xf, 0xf, true));
  x += __int_as_float(__builtin_amdgcn_update_dpp(0, __float_as_int(x), 0x112, 0xf, 0xf, true));
  x += __int_as_float(__builtin_amdgcn_update_dpp(0, __float_as_int(x), 0x114, 0xf, 0xf, true));
  x += __int_as_float(__builtin_amdgcn_update_dpp(0, __float_as_int(x), 0x118, 0xf, 0xf, true));
  x += __int_as_float(__builtin_amdgcn_update_dpp(0, __float_as_int(x), 0x142, 0xf, 0xf, true));
  return x;
}

// ---------------------------------------------------------------------------
// K1: v_shaped = v_template + shapedirs @ betas. 2 rows per thread ->
// 5 aligned float4 + 1 float2 in, 1 float2 out. 150000 threads.
// ---------------------------------------------------------------------------
__global__ __launch_bounds__(256) void k_shape(
    const float* __restrict__ betas, const float* __restrict__ v_template,
    const float* __restrict__ shapedirs, float* __restrict__ v_shaped) {
  __shared__ float sb[10];
  if (threadIdx.x < 10) sb[threadIdx.x] = betas[threadIdx.x];
  __syncthreads();
  int t = blockIdx.x * 256 + threadIdx.x;  // row-pair index
  if (t >= 3 * NV / 2) return;
  const float4* sd4 = (const float4*)(shapedirs + (size_t)t * 20);
  float4 f0 = sd4[0], f1 = sd4[1], f2 = sd4[2], f3 = sd4[3], f4v = sd4[4];
  float2 vt = ((const float2*)v_template)[t];
  float a = vt.x
          + f0.x * sb[0] + f0.y * sb[1] + f0.z * sb[2] + f0.w * sb[3]
          + f1.x * sb[4] + f1.y * sb[5] + f1.z * sb[6] + f1.w * sb[7]
          + f2.x * sb[8] + f2.y * sb[9];
  float b = vt.y
          + f2.z * sb[0] + f2.w * sb[1]
          + f3.x * sb[2] + f3.y * sb[3] + f3.z * sb[4] + f3.w * sb[5]
          + f4v.x * sb[6] + f4v.y * sb[7] + f4v.z * sb[8] + f4v.w * sb[9];
  ((float2*)v_shaped)[t] = make_float2(a, b);
}

// ---------------------------------------------------------------------------
// K2: J partials. grid = (24 joints, 25 parts), pure float4 loads.
// Writes TRANSPOSED jpT[(j*3+k)*32 + part] for contiguous consumer reads.
// ---------------------------------------------------------------------------
__global__ __launch_bounds__(256) void k_jreg(
    const float* __restrict__ Jreg, const float* __restrict__ v_shaped,
    float* __restrict__ jpT) {
  int j = blockIdx.x, part = blockIdx.y, tid = threadIdx.x;
  const int SL = NV / NPART;  // 4000
  int v0 = part * SL;
  const float4* w4 = (const float4*)(Jreg + (size_t)j * NV + v0);
  const float4* s4 = (const float4*)(v_shaped + (size_t)3 * v0);
  float s0 = 0.f, s1 = 0.f, s2 = 0.f;
  for (int i4 = tid; i4 < SL / 4; i4 += 256) {
    float4 w = w4[i4];
    float4 A = s4[3 * i4 + 0];
    float4 B = s4[3 * i4 + 1];
    float4 C = s4[3 * i4 + 2];
    s0 += w.x * A.x + w.y * A.w + w.z * B.z + w.w * C.y;
    s1 += w.x * A.y + w.y * B.x + w.z * B.w + w.w * C.z;
    s2 += w.x * A.z + w.y * B.y + w.z * C.x + w.w * C.w;
  }
  __shared__ float red[256][3];
  red[tid][0] = s0; red[tid][1] = s1; red[tid][2] = s2;
  __syncthreads();
  for (int off = 128; off > 0; off >>= 1) {
    if (tid < off) {
      red[tid][0] += red[tid + off][0];
      red[tid][1] += red[tid + off][1];
      red[tid][2] += red[tid + off][2];
    }
    __syncthreads();
  }
  if (tid < 3) jpT[(j * 3 + tid) * 32 + part] = red[0][tid];
}

// ---------------------------------------------------------------------------
// Stage one 4-vertex posedirs chunk (621 float4, padded dest 640) into this
// wave's LDS buffer. 10 per-wave global_load_lds; src clamped (pad absorbs
// dup writes); vmcnt is per-wave so no cross-wave uniformity needed.
// ---------------------------------------------------------------------------
__device__ __forceinline__ void stage_quad(float4* dst, const float4* src, int lane) {
  #pragma unroll
  for (int r = 0; r < 10; ++r) {
    int i4 = r * 64 + lane;
    int i4c = (i4 < 621) ? i4 : 620;
    __builtin_amdgcn_global_load_lds(
        (const __attribute__((address_space(1))) void*)(src + i4c),
        (__attribute__((address_space(3))) void*)(dst + r * 64),
        16, 0, 0);
  }
}

// ---------------------------------------------------------------------------
// K3: fused FK + pose-blend + LBS, barrier-free per-wave pipeline (R15).
// ONLY change vs R15: the two 5-round shfl_xor reduce trees are replaced by
// DPP row_shr/bcast adds (VALU pipe) + ONE shfl broadcast per value --
// LDS-pipe ops per pass drop 54 -> 30, relieving contention with the DMA's
// LDS writes.
// ---------------------------------------------------------------------------
__global__ __launch_bounds__(256, 2) void k_fused(
    const float* __restrict__ posedirs, const float* __restrict__ wgt,
    const float* __restrict__ pose, const float* __restrict__ jpT,
    const float* __restrict__ scale, const float* __restrict__ trans,
    float* __restrict__ vbuf) {
  __shared__ float4 buf[4][2][640];   // 81920 B = 2 blocks/CU exactly
  int tid = threadIdx.x, b = blockIdx.x;
  int wid = tid >> 6, lane = tid & 63, half = lane >> 5, lj = lane & 31;
  int W = b * 4 + wid;                // wave id 0..2047
  const float4* pd4 = (const float4*)posedirs;

  // P_0 scalars + S_0 stage for quad W
  int q0 = W;
  float pvl0 = (lj < 3) ? vbuf[(size_t)3 * (q0 * 4 + half) + lj] : 0.f;
  float wj0  = (lj < NJ) ? wgt[(size_t)(q0 * 4 + half) * NJ + lj] : 0.f;
  float pvl1 = (lj < 3) ? vbuf[(size_t)3 * (q0 * 4 + 2 + half) + lj] : 0.f;
  float wj1  = (lj < NJ) ? wgt[(size_t)(q0 * 4 + 2 + half) * NJ + lj] : 0.f;
  __builtin_amdgcn_sched_barrier(0);
  stage_quad(&buf[wid][0][0], pd4 + (size_t)q0 * 621, lane);

  // ---- FK in buf[0][1] scratch (dead before any wave stages into it) ----
  float* fkJ  = (float*)&buf[0][1][0];  // [24*3]
  float* fkR  = fkJ + 72;               // [24*9]
  float* fkG  = fkJ + 288;              // [24*12]
  float* lrs  = fkJ + 576;              // [207]
  float* relS = fkJ + 784;              // [24*12]
  if (tid < NJ * 3) {
    const float* src = jpT + tid * 32;
    float a = 0.f;
    #pragma unroll
    for (int i = 0; i < NPART; ++i) a += src[i];
    fkJ[tid] = a;
  }
  if (tid < NJ) {
    float rx = pose[tid * 3 + 0], ry = pose[tid * 3 + 1], rz = pose[tid * 3 + 2];
    float tx = rx + 1e-8f, ty = ry + 1e-8f, tz = rz + 1e-8f;
    float theta = sqrtf(tx * tx + ty * ty + tz * tz);
    float x = rx / theta, y = ry / theta, z = rz / theta;
    float c = cosf(theta), s = sinf(theta), C = 1.f - c;
    float Rr[9];
    Rr[0] = c + C * x * x;     Rr[1] = C * x * y - s * z; Rr[2] = C * x * z + s * y;
    Rr[3] = C * x * y + s * z; Rr[4] = c + C * y * y;     Rr[5] = C * y * z - s * x;
    Rr[6] = C * x * z - s * y; Rr[7] = C * y * z + s * x; Rr[8] = c + C * z * z;
    #pragma unroll
    for (int e = 0; e < 9; ++e) fkR[tid * 9 + e] = Rr[e];
    if (tid >= 1) {
      #pragma unroll
      for (int e = 0; e < 9; ++e) {
        float id = (e == 0 || e == 4 || e == 8) ? 1.f : 0.f;
        lrs[(tid - 1) * 9 + e] = Rr[e] - id;
      }
    }
  }
  __syncthreads();
  if (tid < 3) {  // row-parallel chain: lane a owns row a of all G_i
    const int par[NJ] = {-1,0,0,0,1,2,3,4,5,6,7,8,9,9,9,12,13,14,16,17,18,19,20,21};
    int a = tid;
    fkG[a * 4 + 0] = fkR[a * 3 + 0];
    fkG[a * 4 + 1] = fkR[a * 3 + 1];
    fkG[a * 4 + 2] = fkR[a * 3 + 2];
    fkG[a * 4 + 3] = fkJ[a];
    #pragma unroll
    for (int i = 1; i < NJ; ++i) {
      int p = par[i];
      float t0 = fkJ[i * 3 + 0] - fkJ[p * 3 + 0];
      float t1 = fkJ[i * 3 + 1] - fkJ[p * 3 + 1];
      float t2 = fkJ[i * 3 + 2] - fkJ[p * 3 + 2];
      float g0 = fkG[p * 12 + a * 4 + 0], g1 = fkG[p * 12 + a * 4 + 1];
      float g2 = fkG[p * 12 + a * 4 + 2], g3 = fkG[p * 12 + a * 4 + 3];
      fkG[i * 12 + a * 4 + 0] = g0 * fkR[i * 9 + 0] + g1 * fkR[i * 9 + 3] + g2 * fkR[i * 9 + 6];
      fkG[i * 12 + a * 4 + 1] = g0 * fkR[i * 9 + 1] + g1 * fkR[i * 9 + 4] + g2 * fkR[i * 9 + 7];
      fkG[i * 12 + a * 4 + 2] = g0 * fkR[i * 9 + 2] + g1 * fkR[i * 9 + 5] + g2 * fkR[i * 9 + 8];
      fkG[i * 12 + a * 4 + 3] = g3 + g0 * t0 + g1 * t1 + g2 * t2;
    }
  }
  __syncthreads();
  if (tid < NJ) {
    #pragma unroll
    for (int a = 0; a < 3; ++a) {
      float corr = fkG[tid * 12 + a * 4 + 0] * fkJ[tid * 3 + 0] +
                   fkG[tid * 12 + a * 4 + 1] * fkJ[tid * 3 + 1] +
                   fkG[tid * 12 + a * 4 + 2] * fkJ[tid * 3 + 2];
      relS[tid * 12 + a * 4 + 0] = fkG[tid * 12 + a * 4 + 0];
      relS[tid * 12 + a * 4 + 1] = fkG[tid * 12 + a * 4 + 1];
      relS[tid * 12 + a * 4 + 2] = fkG[tid * 12 + a * 4 + 2];
      relS[tid * 12 + a * 4 + 3] = fkG[tid * 12 + a * 4 + 3] - corr;
    }
  }
  __syncthreads();

  float llr[7];
  #pragma unroll
  for (int e = 0; e < 7; ++e) {
    int p = lj + 32 * e;
    llr[e] = (p < NP) ? lrs[p] : 0.f;
  }
  float rlq[12];
  #pragma unroll
  for (int e = 0; e < 12; ++e) rlq[e] = (lj < NJ) ? relS[lj * 12 + e] : 0.f;
  float sc = scale[0];
  float tr = (lj < 3) ? trans[lj] : 0.f;

  __syncthreads();  // scratch reads done; buf[0][1] may be staged from now on
  asm volatile("s_waitcnt vmcnt(0)" ::: "memory");  // clean per-wave base

  int nt = (NQUADS - 1 - W) / NWV + 1;  // per-wave; no uniformity needed
  for (int it = 0; it < nt; ++it) {
    int cur = it & 1;
    int qn = W + (it + 1) * NWV;
    if (qn >= NQUADS) qn = NQUADS - 1;  // dummy on last iter
    float pvl0_n = (lj < 3) ? vbuf[(size_t)3 * (qn * 4 + half) + lj] : 0.f;
    float wj0_n  = (lj < NJ) ? wgt[(size_t)(qn * 4 + half) * NJ + lj] : 0.f;
    float pvl1_n = (lj < 3) ? vbuf[(size_t)3 * (qn * 4 + 2 + half) + lj] : 0.f;
    float wj1_n  = (lj < NJ) ? wgt[(size_t)(qn * 4 + 2 + half) * NJ + lj] : 0.f;
    __builtin_amdgcn_sched_barrier(0);
    stage_quad(&buf[wid][cur ^ 1][0], pd4 + (size_t)qn * 621, lane);
    asm volatile("s_waitcnt vmcnt(14)" ::: "memory");
    __builtin_amdgcn_sched_barrier(0);

    int q = W + it * NWV;
    const float* chunk = (const float*)&buf[wid][cur][0];
    #pragma unroll
    for (int h = 0; h < 2; ++h) {
      int vv = q * 4 + 2 * h + half;
      const float* row = chunk + (2 * h + half) * (3 * NP);
      float pvl = h ? pvl1 : pvl0;
      float wj  = h ? wj1 : wj0;
      float a0 = 0.f, a1 = 0.f, a2 = 0.f;
      #pragma unroll
      for (int e = 0; e < 7; ++e) {
        int p = lj + 32 * e;
        if (p < NP) {
          float l = llr[e];
          a0 += row[p] * l;
          a1 += row[NP + p] * l;
          a2 += row[2 * NP + p] * l;
        }
      }
      int gb = lane & 32;
      a0 = __shfl(dpp_red32(a0), gb + 31);
      a1 = __shfl(dpp_red32(a1), gb + 31);
      a2 = __shfl(dpp_red32(a2), gb + 31);
      float p0 = __shfl(pvl, gb + 0) + a0;
      float p1 = __shfl(pvl, gb + 1) + a1;
      float p2 = __shfl(pvl, gb + 2) + a2;
      float q0v = rlq[0] * p0 + rlq[1] * p1 + rlq[2]  * p2 + rlq[3];
      float q1v = rlq[4] * p0 + rlq[5] * p1 + rlq[6]  * p2 + rlq[7];
      float q2v = rlq[8] * p0 + rlq[9] * p1 + rlq[10] * p2 + rlq[11];
      float r0 = dpp_red32(wj * q0v);
      float r1 = dpp_red32(wj * q1v);
      float r2 = dpp_red32(wj * q2v);
      r0 = __shfl(r0, gb + 31);
      r1 = __shfl(r1, gb + 31);
      r2 = __shfl(r2, gb + 31);
      if (lj < 3) {
        float oo = (lj == 0) ? r0 : (lj == 1) ? r1 : r2;
        vbuf[(size_t)3 * vv + lj] = oo * sc + tr;
      }
    }
    pvl0 = pvl0_n; wj0 = wj0_n; pvl1 = pvl1_n; wj1 = wj1_n;
  }
  asm volatile("s_waitcnt vmcnt(0)" ::: "memory");  // drain tail dummies
}

extern "C" void kernel_launch(void* const* d_in, const int* in_sizes, int n_in,
                              void* d_out, int out_size, void* d_ws, size_t ws_size,
                              hipStream_t stream) {
  const float* betas      = (const float*)d_in[0];
  const float* pose       = (const float*)d_in[1];
  const float* scale      = (const float*)d_in[2];
  const float* trans      = (const float*)d_in[3];
  const float* v_template = (const float*)d_in[4];
  const float* shapedirs  = (const float*)d_in[5];
  const float* posedirs   = (const float*)d_in[6];
  const float* Jreg       = (const float*)d_in[7];
  const float* weights    = (const float*)d_in[8];
  float* out = (float*)d_out;
  float* ws  = (float*)d_ws;

  float* jpT = ws;  // 72*32 = 2304 floats

  k_shape<<<(3 * NV / 2 + 255) / 256, 256, 0, stream>>>(betas, v_template, shapedirs, out);
  k_jreg<<<dim3(NJ, NPART), 256, 0, stream>>>(Jreg, out, jpT);
  k_fused<<<GRIDF, 256, 0, stream>>>(posedirs, weights, pose, jpT, scale, trans, out);
}

// Round 17
// 57.994 us; speedup vs baseline: 1.4885x; 1.0311x over previous
//
#include <hip/hip_runtime.h>

#define NV 100000
#define NJ 24
#define NP 207
#define NPART 25
#define NPAIRS (NV / 2)        // 50000 2-vertex pairs
#define GRIDF 1024
#define NWV (GRIDF * 4)        // 4096 waves (even -> pair parity = W parity)

// ---------------------------------------------------------------------------
// DPP 32-lane-group sum (VALU pipe). Lane 31 holds sum(0..31), 63 sum(32..63).
// ---------------------------------------------------------------------------
__device__ __forceinline__ float dpp_red32(float x) {
  x += __int_as_float(__builtin_amdgcn_update_dpp(0, __float_as_int(x), 0x111, 0xf, 0xf, true));
  x += __int_as_float(__builtin_amdgcn_update_dpp(0, __float_as_int(x), 0x112, 0xf, 0xf, true));
  x += __int_as_float(__builtin_amdgcn_update_dpp(0, __float_as_int(x), 0x114, 0xf, 0xf, true));
  x += __int_as_float(__builtin_amdgcn_update_dpp(0, __float_as_int(x), 0x118, 0xf, 0xf, true));
  x += __int_as_float(__builtin_amdgcn_update_dpp(0, __float_as_int(x), 0x142, 0xf, 0xf, true));
  return x;
}

// ---------------------------------------------------------------------------
// K1: v_shaped = v_template + shapedirs @ betas. 2 rows/thread, float4 loads.
// ---------------------------------------------------------------------------
__global__ __launch_bounds__(256) void k_shape(
    const float* __restrict__ betas, const float* __restrict__ v_template,
    const float* __restrict__ shapedirs, float* __restrict__ v_shaped) {
  __shared__ float sb[10];
  if (threadIdx.x < 10) sb[threadIdx.x] = betas[threadIdx.x];
  __syncthreads();
  int t = blockIdx.x * 256 + threadIdx.x;  // row-pair index
  if (t >= 3 * NV / 2) return;
  const float4* sd4 = (const float4*)(shapedirs + (size_t)t * 20);
  float4 f0 = sd4[0], f1 = sd4[1], f2 = sd4[2], f3 = sd4[3], f4v = sd4[4];
  float2 vt = ((const float2*)v_template)[t];
  float a = vt.x
          + f0.x * sb[0] + f0.y * sb[1] + f0.z * sb[2] + f0.w * sb[3]
          + f1.x * sb[4] + f1.y * sb[5] + f1.z * sb[6] + f1.w * sb[7]
          + f2.x * sb[8] + f2.y * sb[9];
  float b = vt.y
          + f2.z * sb[0] + f2.w * sb[1]
          + f3.x * sb[2] + f3.y * sb[3] + f3.z * sb[4] + f3.w * sb[5]
          + f4v.x * sb[6] + f4v.y * sb[7] + f4v.z * sb[8] + f4v.w * sb[9];
  ((float2*)v_shaped)[t] = make_float2(a, b);
}

// ---------------------------------------------------------------------------
// K2: J partials. grid = (24, 25), float4 loads, transposed jpT output.
// ---------------------------------------------------------------------------
__global__ __launch_bounds__(256) void k_jreg(
    const float* __restrict__ Jreg, const float* __restrict__ v_shaped,
    float* __restrict__ jpT) {
  int j = blockIdx.x, part = blockIdx.y, tid = threadIdx.x;
  const int SL = NV / NPART;  // 4000
  int v0 = part * SL;
  const float4* w4 = (const float4*)(Jreg + (size_t)j * NV + v0);
  const float4* s4 = (const float4*)(v_shaped + (size_t)3 * v0);
  float s0 = 0.f, s1 = 0.f, s2 = 0.f;
  for (int i4 = tid; i4 < SL / 4; i4 += 256) {
    float4 w = w4[i4];
    float4 A = s4[3 * i4 + 0];
    float4 B = s4[3 * i4 + 1];
    float4 C = s4[3 * i4 + 2];
    s0 += w.x * A.x + w.y * A.w + w.z * B.z + w.w * C.y;
    s1 += w.x * A.y + w.y * B.x + w.z * B.w + w.w * C.z;
    s2 += w.x * A.z + w.y * B.y + w.z * C.x + w.w * C.w;
  }
  __shared__ float red[256][3];
  red[tid][0] = s0; red[tid][1] = s1; red[tid][2] = s2;
  __syncthreads();
  for (int off = 128; off > 0; off >>= 1) {
    if (tid < off) {
      red[tid][0] += red[tid + off][0];
      red[tid][1] += red[tid + off][1];
      red[tid][2] += red[tid + off][2];
    }
    __syncthreads();
  }
  if (tid < 3) jpT[(j * 3 + tid) * 32 + part] = red[0][tid];
}

// ---------------------------------------------------------------------------
// Stage one 2-vertex pair window (311 float4, dest padded to 320) into this
// wave's LDS buffer. Src is the pair's float range rounded DOWN to a float4
// boundary (always 16B-aligned); odd pairs carry a +2-float LDS offset,
// folded into the (wave-constant) row pointer. Clamped tail; pad absorbs.
// ---------------------------------------------------------------------------
__device__ __forceinline__ void stage_pair(float4* dst, const float4* src, int lane) {
  #pragma unroll
  for (int r = 0; r < 5; ++r) {
    int i4 = r * 64 + lane;
    int i4c = (i4 < 311) ? i4 : 310;
    __builtin_amdgcn_global_load_lds(
        (const __attribute__((address_space(1))) void*)(src + i4c),
        (__attribute__((address_space(3))) void*)(dst + r * 64),
        16, 0, 0);
  }
}

__device__ __forceinline__ const float4* pair_src(const float* posedirs, int p) {
  size_t startf = (size_t)1242 * p - ((p & 1) ? 2 : 0);  // multiple of 4
  return (const float4*)(posedirs + startf);
}

// ---------------------------------------------------------------------------
// K3: fused FK + pose-blend + LBS, barrier-free per-wave pipeline.
// Chunk = 2-vertex pair -> 10KB LDS/wave -> 4 blocks/CU = 16 waves/CU
// (vs 8 before): double the TLP at the same in-flight bytes. Per iter:
// 2 scalar prefetches + 5 stage ops -> vmcnt(7) drains exactly the previous
// iter's 7 (a full iteration old -> no stall) -> one 2-vertex compute pass.
// ---------------------------------------------------------------------------
__global__ __launch_bounds__(256, 4) void k_fused(
    const float* __restrict__ posedirs, const float* __restrict__ wgt,
    const float* __restrict__ pose, const float* __restrict__ jpT,
    const float* __restrict__ scale, const float* __restrict__ trans,
    float* __restrict__ vbuf) {
  __shared__ float4 buf[4][2][320];   // 40960 B = 4 blocks/CU exactly
  int tid = threadIdx.x, b = blockIdx.x;
  int wid = tid >> 6, lane = tid & 63, half = lane >> 5, lj = lane & 31;
  int W = b * 4 + wid;                // wave id 0..4095
  int sh = (W & 1) ? 2 : 0;           // pair parity == W parity (NWV even)

  // P_0 scalars + S_0 stage for pair W
  float pvl = (lj < 3) ? vbuf[(size_t)3 * (W * 2 + half) + lj] : 0.f;
  float wj  = (lj < NJ) ? wgt[(size_t)(W * 2 + half) * NJ + lj] : 0.f;
  __builtin_amdgcn_sched_barrier(0);
  stage_pair(&buf[wid][0][0], pair_src(posedirs, W), lane);

  // ---- FK in buf[0][1] scratch (staged only at iter 0, after final sync) ----
  float* fkJ  = (float*)&buf[0][1][0];  // [24*3]
  float* fkR  = fkJ + 72;               // [24*9]
  float* fkG  = fkJ + 288;              // [24*12]
  float* lrs  = fkJ + 576;              // [207]
  float* relS = fkJ + 784;              // [24*12]  (total 1072 fl = 4288 B <= 5120)
  if (tid < NJ * 3) {
    const float* src = jpT + tid * 32;
    float a = 0.f;
    #pragma unroll
    for (int i = 0; i < NPART; ++i) a += src[i];
    fkJ[tid] = a;
  }
  if (tid < NJ) {
    float rx = pose[tid * 3 + 0], ry = pose[tid * 3 + 1], rz = pose[tid * 3 + 2];
    float tx = rx + 1e-8f, ty = ry + 1e-8f, tz = rz + 1e-8f;
    float theta = sqrtf(tx * tx + ty * ty + tz * tz);
    float x = rx / theta, y = ry / theta, z = rz / theta;
    float c = cosf(theta), s = sinf(theta), C = 1.f - c;
    float Rr[9];
    Rr[0] = c + C * x * x;     Rr[1] = C * x * y - s * z; Rr[2] = C * x * z + s * y;
    Rr[3] = C * x * y + s * z; Rr[4] = c + C * y * y;     Rr[5] = C * y * z - s * x;
    Rr[6] = C * x * z - s * y; Rr[7] = C * y * z + s * x; Rr[8] = c + C * z * z;
    #pragma unroll
    for (int e = 0; e < 9; ++e) fkR[tid * 9 + e] = Rr[e];
    if (tid >= 1) {
      #pragma unroll
      for (int e = 0; e < 9; ++e) {
        float id = (e == 0 || e == 4 || e == 8) ? 1.f : 0.f;
        lrs[(tid - 1) * 9 + e] = Rr[e] - id;
      }
    }
  }
  __syncthreads();
  if (tid < 3) {  // row-parallel chain: lane a owns row a of all G_i
    const int par[NJ] = {-1,0,0,0,1,2,3,4,5,6,7,8,9,9,9,12,13,14,16,17,18,19,20,21};
    int a = tid;
    fkG[a * 4 + 0] = fkR[a * 3 + 0];
    fkG[a * 4 + 1] = fkR[a * 3 + 1];
    fkG[a * 4 + 2] = fkR[a * 3 + 2];
    fkG[a * 4 + 3] = fkJ[a];
    #pragma unroll
    for (int i = 1; i < NJ; ++i) {
      int p = par[i];
      float t0 = fkJ[i * 3 + 0] - fkJ[p * 3 + 0];
      float t1 = fkJ[i * 3 + 1] - fkJ[p * 3 + 1];
      float t2 = fkJ[i * 3 + 2] - fkJ[p * 3 + 2];
      float g0 = fkG[p * 12 + a * 4 + 0], g1 = fkG[p * 12 + a * 4 + 1];
      float g2 = fkG[p * 12 + a * 4 + 2], g3 = fkG[p * 12 + a * 4 + 3];
      fkG[i * 12 + a * 4 + 0] = g0 * fkR[i * 9 + 0] + g1 * fkR[i * 9 + 3] + g2 * fkR[i * 9 + 6];
      fkG[i * 12 + a * 4 + 1] = g0 * fkR[i * 9 + 1] + g1 * fkR[i * 9 + 4] + g2 * fkR[i * 9 + 7];
      fkG[i * 12 + a * 4 + 2] = g0 * fkR[i * 9 + 2] + g1 * fkR[i * 9 + 5] + g2 * fkR[i * 9 + 8];
      fkG[i * 12 + a * 4 + 3] = g3 + g0 * t0 + g1 * t1 + g2 * t2;
    }
  }
  __syncthreads();
  if (tid < NJ) {
    #pragma unroll
    for (int a = 0; a < 3; ++a) {
      float corr = fkG[tid * 12 + a * 4 + 0] * fkJ[tid * 3 + 0] +
                   fkG[tid * 12 + a * 4 + 1] * fkJ[tid * 3 + 1] +
                   fkG[tid * 12 + a * 4 + 2] * fkJ[tid * 3 + 2];
      relS[tid * 12 + a * 4 + 0] = fkG[tid * 12 + a * 4 + 0];
      relS[tid * 12 + a * 4 + 1] = fkG[tid * 12 + a * 4 + 1];
      relS[tid * 12 + a * 4 + 2] = fkG[tid * 12 + a * 4 + 2];
      relS[tid * 12 + a * 4 + 3] = fkG[tid * 12 + a * 4 + 3] - corr;
    }
  }
  __syncthreads();

  float llr[7];
  #pragma unroll
  for (int e = 0; e < 7; ++e) {
    int p = lj + 32 * e;
    llr[e] = (p < NP) ? lrs[p] : 0.f;
  }
  float rlq[12];
  #pragma unroll
  for (int e = 0; e < 12; ++e) rlq[e] = (lj < NJ) ? relS[lj * 12 + e] : 0.f;
  float sc = scale[0];
  float tr = (lj < 3) ? trans[lj] : 0.f;

  __syncthreads();  // scratch reads done; buf[0][1] may be staged from now on
  asm volatile("s_waitcnt vmcnt(0)" ::: "memory");  // clean per-wave base

  int nt = (NPAIRS - 1 - W) / NWV + 1;  // per-wave trip count
  for (int it = 0; it < nt; ++it) {
    int cur = it & 1;
    int pn = W + (it + 1) * NWV;
    if (pn >= NPAIRS) pn = NPAIRS - 1;  // dummy on last iter (same parity)
    float pvl_n = (lj < 3) ? vbuf[(size_t)3 * (pn * 2 + half) + lj] : 0.f;
    float wj_n  = (lj < NJ) ? wgt[(size_t)(pn * 2 + half) * NJ + lj] : 0.f;
    __builtin_amdgcn_sched_barrier(0);
    stage_pair(&buf[wid][cur ^ 1][0], pair_src(posedirs, pn), lane);
    asm volatile("s_waitcnt vmcnt(7)" ::: "memory");
    __builtin_amdgcn_sched_barrier(0);

    int p = W + it * NWV;
    int vv = p * 2 + half;
    const float* row = (const float*)&buf[wid][cur][0] + sh + half * (3 * NP);
    float a0 = 0.f, a1 = 0.f, a2 = 0.f;
    #pragma unroll
    for (int e = 0; e < 7; ++e) {
      int pp = lj + 32 * e;
      if (pp < NP) {
        float l = llr[e];
        a0 += row[pp] * l;
        a1 += row[NP + pp] * l;
        a2 += row[2 * NP + pp] * l;
      }
    }
    int gb = lane & 32;
    a0 = __shfl(dpp_red32(a0), gb + 31);
    a1 = __shfl(dpp_red32(a1), gb + 31);
    a2 = __shfl(dpp_red32(a2), gb + 31);
    float p0 = __shfl(pvl, gb + 0) + a0;
    float p1 = __shfl(pvl, gb + 1) + a1;
    float p2 = __shfl(pvl, gb + 2) + a2;
    float q0v = rlq[0] * p0 + rlq[1] * p1 + rlq[2]  * p2 + rlq[3];
    float q1v = rlq[4] * p0 + rlq[5] * p1 + rlq[6]  * p2 + rlq[7];
    float q2v = rlq[8] * p0 + rlq[9] * p1 + rlq[10] * p2 + rlq[11];
    float r0 = __shfl(dpp_red32(wj * q0v), gb + 31);
    float r1 = __shfl(dpp_red32(wj * q1v), gb + 31);
    float r2 = __shfl(dpp_red32(wj * q2v), gb + 31);
    if (lj < 3) {
      float oo = (lj == 0) ? r0 : (lj == 1) ? r1 : r2;
      vbuf[(size_t)3 * vv + lj] = oo * sc + tr;
    }
    pvl = pvl_n; wj = wj_n;
  }
  asm volatile("s_waitcnt vmcnt(0)" ::: "memory");  // drain tail dummies
}

extern "C" void kernel_launch(void* const* d_in, const int* in_sizes, int n_in,
                              void* d_out, int out_size, void* d_ws, size_t ws_size,
                              hipStream_t stream) {
  const float* betas      = (const float*)d_in[0];
  const float* pose       = (const float*)d_in[1];
  const float* scale      = (const float*)d_in[2];
  const float* trans      = (const float*)d_in[3];
  const float* v_template = (const float*)d_in[4];
  const float* shapedirs  = (const float*)d_in[5];
  const float* posedirs   = (const float*)d_in[6];
  const float* Jreg       = (const float*)d_in[7];
  const float* weights    = (const float*)d_in[8];
  float* out = (float*)d_out;
  float* ws  = (float*)d_ws;

  float* jpT = ws;  // 72*32 = 2304 floats

  k_shape<<<(3 * NV / 2 + 255) / 256, 256, 0, stream>>>(betas, v_template, shapedirs, out);
  k_jreg<<<dim3(NJ, NPART), 256, 0, stream>>>(Jreg, out, jpT);
  k_fused<<<GRIDF, 256, 0, stream>>>(posedirs, weights, pose, jpT, scale, trans, out);
}